// Round 4
// baseline (301.906 us; speedup 1.0000x reference)
//
#include <hip/hip_runtime.h>
#include <hip/hip_bf16.h>

typedef unsigned short u16;
typedef __attribute__((ext_vector_type(4))) unsigned short u16x4;
typedef __attribute__((ext_vector_type(8))) unsigned short u16x8;
typedef __attribute__((ext_vector_type(8))) __bf16 bf16x8;
typedef __attribute__((ext_vector_type(4))) float f32x4;

#define BB 16
#define TSEQ 1024
#define CC 584          /* embed dim */
#define HH 8
#define DHD 73
#define NR (BB*TSEQ)    /* 16384 rows */
#define KPW 640         /* padded K: 10 x 64 -> 5 iters x 2 K-tiles */
#define DP 96           /* padded head dim */
#define HD (HH*DP)      /* 768 */
#define NP3 768         /* padded N for final proj (3 x 256 tiles) */
#define PPITCH 88
/* exp(s*584^-0.5) == exp2(s * CEXP); scores bounded -> no max subtraction */
#define CEXP 0.0596985934f

__device__ __forceinline__ u16 f2bf(float f) {
  __bf16 h = (__bf16)f;                 // native v_cvt, RNE
  return __builtin_bit_cast(u16, h);
}
__device__ __forceinline__ bf16x8 as_bf(u16x8 v) { return __builtin_bit_cast(bf16x8, v); }

/* async global->LDS, 16B/lane, LDS dst = wave-uniform base + lane*16 */
#define GLL16(g, l) __builtin_amdgcn_global_load_lds( \
    (const __attribute__((address_space(1))) void*)(g), \
    (__attribute__((address_space(3))) void*)(l), 16, 0, 0)

#define BARRIER() asm volatile("s_barrier" ::: "memory")
#define LGKM0()   asm volatile("s_waitcnt lgkmcnt(0)" ::: "memory")
#define VMW8()    asm volatile("s_waitcnt vmcnt(8)" ::: "memory")
#define VMW4()    asm volatile("s_waitcnt vmcnt(4)" ::: "memory")
#define VMW0()    asm volatile("s_waitcnt vmcnt(0)" ::: "memory")

// ---------------- fused pack kernel ----------------
// phase A (10240 blocks): x|mem [16384,584] f32 -> xmb [32768][640] bf16 zero-pad
//   (streaming, BW-bound: 1 chunk/thread)
// phase B (720 blocks x 2048 elems): Wq/Wv/Wk -> wt [q|v|k 768 rows][640] bf16
// phase C (240 blocks x 2048 elems): Wp -> wpt [768][640] bf16 (transposed)
//   (B/C are latency-bound gathers: 8 elems/thread cuts dispatch rounds 30->3.75)
#define PKA 10240
#define PKB2 720
#define PKC2 240
__global__ void pack_all_kernel(const float* __restrict__ x, const float* __restrict__ mem,
                                const float* __restrict__ Wq, const float* __restrict__ Wk,
                                const float* __restrict__ Wv, const float* __restrict__ Wp,
                                u16* __restrict__ xmb, u16* __restrict__ wt,
                                u16* __restrict__ wpt) {
  const int bidx = blockIdx.x;
  const int tid = threadIdx.x;
  if (bidx < PKA) {
    int idx = bidx * 256 + tid;
    int row = idx / (KPW / 8);
    int c8  = (idx % (KPW / 8)) * 8;
    u16x8 o = {0, 0, 0, 0, 0, 0, 0, 0};
    if (c8 < CC) {
      const float* src = (row < NR) ? &x[(size_t)row * CC + c8]
                                    : &mem[(size_t)(row - NR) * CC + c8];
      f32x4 a = *(const f32x4*)src;
      f32x4 b = *(const f32x4*)(src + 4);
#pragma unroll
      for (int t = 0; t < 4; t++) { o[t] = f2bf(a[t]); o[4 + t] = f2bf(b[t]); }
    }
    *(u16x8*)&xmb[(size_t)row * KPW + c8] = o;
  } else if (bidx < PKA + PKB2) {
    const int base = (bidx - PKA) * 2048 + tid;
#pragma unroll
    for (int e = 0; e < 8; e++) {
      int idx = base + e * 256;
      int w   = idx / (HD * KPW);
      int rem = idx % (HD * KPW);
      int n = rem / KPW;
      int k = rem % KPW;
      int h = n / DP, d = n % DP;
      u16 val = 0;
      if (d < DHD && k < CC) {
        const float* W = (w == 0) ? Wq : ((w == 1) ? Wv : Wk);  // order: q, v, k
        val = f2bf(W[((size_t)h * CC + k) * DHD + d]);
      }
      wt[idx] = val;
    }
  } else {
    const int base = (bidx - PKA - PKB2) * 2048 + tid;
#pragma unroll
    for (int e = 0; e < 8; e++) {
      int idx = base + e * 256;
      int n = idx / KPW;
      int c = idx % KPW;
      u16 val = 0;
      if (n < CC && c < CC) val = f2bf(Wp[(size_t)c * CC + n]);
      wpt[idx] = val;
    }
  }
}

// ---------------- 256x256 8-phase GEMM, deep-pipelined staging ----------------
// 512 threads = 8 waves; wave rows = mh*128 + wmi*64 + [0,64), cols = nh*128 +
// wni*32 + [0,32). LDS (128 KiB, 2 bufs): per buf A0|A1|B0|B1 regions of 8192
// u16 (128 rows x 64 K). Per phase: {ds_reads for quadrant; [burst-stage 4
// gl_lds + vmcnt(8)]; barrier; lgkmcnt(0); setprio(1); 16 MFMA; setprio(0);
// barrier}. A cached over nh, B0/B1 over mh -> 24 ds_read_b128/K-tile/wave.
// Staging (iter i: buf0=T=2i, buf1=T+1). Region last-read map: buf A0,B0 die
// after ph1(ph5), B1 after ph2(ph6), A1 after ph3(ph7). Bursts (pairs):
//   ph1: (T+1).B1A1 -> buf1 ; vmcnt(8) retires T.B1A1   [read ph2/ph3]
//   ph4: (T+2).A0B0 -> buf0 ; vmcnt(8) retires (T+1).A0B0 [read ph5]
//   ph5: (T+2).B1A1 -> buf0 ; vmcnt(8) retires (T+1).B1A1 [read ph6/ph7]
//   ph8: (T+3).A0B0 -> buf1 ; vmcnt(8) retires (T+2).A0B0 [read ph1']
// 8-12 loads in flight, never drained mid-loop, uniform 4-phase slack.
// Tail (i=4): ph4 vmcnt(4), ph5 vmcnt(0). All verified incl. prologue.

template <int BUF, int MH>
__device__ __forceinline__ void rd_a(bf16x8 (&a)[4][2], const u16* lds, int arow,
                                     int sw0, int sw1) {
#pragma unroll
  for (int mq = 0; mq < 4; mq++) {
    const int r = BUF * 32768 + MH * 8192 + arow + mq * 1024;
    a[mq][0] = as_bf(*(const u16x8*)&lds[r + sw0]);
    a[mq][1] = as_bf(*(const u16x8*)&lds[r + sw1]);
  }
}
template <int BUF, int NH>
__device__ __forceinline__ void rd_b(bf16x8 (&b)[2][2], const u16* lds, int brow,
                                     int sw0, int sw1) {
#pragma unroll
  for (int nq = 0; nq < 2; nq++) {
    const int r = BUF * 32768 + 16384 + NH * 8192 + brow + nq * 1024;
    b[nq][0] = as_bf(*(const u16x8*)&lds[r + sw0]);
    b[nq][1] = as_bf(*(const u16x8*)&lds[r + sw1]);
  }
}
// RG: 0=A0, 1=A1, 2=B0, 3=B1 ; half-tile = 128 rows x 64 K = 2 loads/thread
template <int BUF, int RG>
__device__ __forceinline__ void stg(const u16* gA, const u16* gB, u16* ldst, int t) {
  const u16* src = (RG < 2) ? gA : gB;
  const int rrow = (RG & 1) * 128;
  const int loff = BUF * 32768 + (RG >> 1) * 16384 + (RG & 1) * 8192;
  GLL16(src + (size_t)rrow * KPW + (size_t)t * 64, ldst + loff);
  GLL16(src + (size_t)(rrow + 64) * KPW + (size_t)t * 64, ldst + loff + 4096);
}
template <int MH, int NH>
__device__ __forceinline__ void mmq(f32x4 (&acc)[8][4], const bf16x8 (&a)[4][2],
                                    const bf16x8 (&b)[2][2]) {
  __builtin_amdgcn_s_setprio(1);
#pragma unroll
  for (int mq = 0; mq < 4; mq++)
#pragma unroll
    for (int nq = 0; nq < 2; nq++) {
      f32x4 c = acc[MH * 4 + mq][NH * 2 + nq];
      c = __builtin_amdgcn_mfma_f32_16x16x32_bf16(a[mq][0], b[nq][0], c, 0, 0, 0);
      c = __builtin_amdgcn_mfma_f32_16x16x32_bf16(a[mq][1], b[nq][1], c, 0, 0, 0);
      acc[MH * 4 + mq][NH * 2 + nq] = c;
    }
  __builtin_amdgcn_s_setprio(0);
}

// MODE 4: merged projections. MODE 2: final proj + bias -> f32.
template <int MODE>
__global__ __launch_bounds__(512, 2) void gemm8_kernel(
    const u16* __restrict__ A, const u16* __restrict__ Bt,
    void* __restrict__ CoutV, void* __restrict__ CoutV2,
    const float* __restrict__ bias) {
  extern __shared__ u16 lds[];
  const int tid  = threadIdx.x;
  const int lane = tid & 63;
  const int q15  = lane & 15;
  const int quad = lane >> 4;
  const int wave = tid >> 6;
  const int wmi  = wave >> 2;     // 0..1
  const int wni  = wave & 3;      // 0..3

  // XCD-contiguous swizzle (grid % 8 == 0 for both modes)
  const int cpx = gridDim.x >> 3;
  const int bid = (blockIdx.x & 7) * cpx + (blockIdx.x >> 3);

  int m0, n0, npart;  // npart: 0=q 1=v 2=k (MODE4)
  if (MODE == 4) {
    if (bid < 384) {
      m0 = (bid / 6) * 256; int nt = bid % 6;
      n0 = nt * 256; npart = (nt >= 3) ? 1 : 0;
    } else {
      int b2 = bid - 384;
      m0 = NR + (b2 / 3) * 256; n0 = 1536 + (b2 % 3) * 256; npart = 2;
    }
  } else {
    m0 = (bid / 3) * 256; n0 = (bid % 3) * 256; npart = 0;
  }

  // staging geometry: thread t covers (row = t>>3, chunk = t&7) of a 64-row unit;
  // source chunk pre-swizzled so swizzled ds_read finds linear data (T2 rule 21).
  const int tr   = tid >> 3;
  const int scol = ((tid & 7) ^ (tr & 7)) * 8;
  const u16* gA = &A[(size_t)(m0 + tr) * KPW + scol];
  const u16* gB = &Bt[(size_t)(n0 + tr) * KPW + scol];
  u16* ldst = &lds[tid * 8];

  // fragment-read swizzled 16B-slot offsets (frag row & 7 == q15 & 7)
  const int rb  = q15 & 7;
  const int sw0 = (quad ^ rb) * 8;
  const int sw1 = ((quad + 4) ^ rb) * 8;
  const int arow = (wmi * 64 + q15) * 64;
  const int brow = (wni * 32 + q15) * 64;

  f32x4 acc[8][4];
#pragma unroll
  for (int i = 0; i < 8; i++)
#pragma unroll
    for (int j = 0; j < 4; j++) acc[i][j] = (f32x4){0.f, 0.f, 0.f, 0.f};
  bf16x8 a[4][2], b0[2][2], b1[2][2];

  // prologue: T0 all units + T1.A0B0 (12 loads); vmcnt(8) -> T0.A0B0 landed
  stg<0, 0>(gA, gB, ldst, 0);
  stg<0, 2>(gA, gB, ldst, 0);
  stg<0, 3>(gA, gB, ldst, 0);
  stg<0, 1>(gA, gB, ldst, 0);
  stg<1, 0>(gA, gB, ldst, 1);
  stg<1, 2>(gA, gB, ldst, 1);
  VMW8(); BARRIER();

#pragma unroll 1
  for (int i = 0; i < 5; ++i) {
    const int t1 = 2 * i + 1;
    const int t2 = 2 * i + 2;
    const int t3 = 2 * i + 3;
    const bool st = (i < 4);
    // ph1: (0,0) buf0 ; stage (T+1).B1A1 ; wait T.B1A1
    rd_a<0, 0>(a, lds, arow, sw0, sw1);
    rd_b<0, 0>(b0, lds, brow, sw0, sw1);
    stg<1, 3>(gA, gB, ldst, t1);
    stg<1, 1>(gA, gB, ldst, t1);
    VMW8(); BARRIER(); LGKM0();
    mmq<0, 0>(acc, a, b0);
    BARRIER();
    // ph2: (0,1) buf0 (a cached)
    rd_b<0, 1>(b1, lds, brow, sw0, sw1);
    BARRIER(); LGKM0();
    mmq<0, 1>(acc, a, b1);
    BARRIER();
    // ph3: (1,0) buf0 (b0 cached)
    rd_a<0, 1>(a, lds, arow, sw0, sw1);
    BARRIER(); LGKM0();
    mmq<1, 0>(acc, a, b0);
    BARRIER();
    // ph4: (1,1) buf0 ; stage (T+2).A0B0 ; wait (T+1).A0B0
    if (st) { stg<0, 0>(gA, gB, ldst, t2); stg<0, 2>(gA, gB, ldst, t2); VMW8(); }
    else { VMW4(); }
    BARRIER();
    mmq<1, 1>(acc, a, b1);
    BARRIER();
    // ph5: (0,0) buf1 ; stage (T+2).B1A1 ; wait (T+1).B1A1
    rd_a<1, 0>(a, lds, arow, sw0, sw1);
    rd_b<1, 0>(b0, lds, brow, sw0, sw1);
    if (st) { stg<0, 3>(gA, gB, ldst, t2); stg<0, 1>(gA, gB, ldst, t2); VMW8(); }
    else { VMW0(); }
    BARRIER(); LGKM0();
    mmq<0, 0>(acc, a, b0);
    BARRIER();
    // ph6: (0,1) buf1
    rd_b<1, 1>(b1, lds, brow, sw0, sw1);
    BARRIER(); LGKM0();
    mmq<0, 1>(acc, a, b1);
    BARRIER();
    // ph7: (1,0) buf1
    rd_a<1, 1>(a, lds, arow, sw0, sw1);
    BARRIER(); LGKM0();
    mmq<1, 0>(acc, a, b0);
    BARRIER();
    // ph8: (1,1) buf1 ; stage (T+3).A0B0 ; wait (T+2).A0B0
    if (st) { stg<1, 0>(gA, gB, ldst, t3); stg<1, 2>(gA, gB, ldst, t3); VMW8(); }
    BARRIER();
    mmq<1, 1>(acc, a, b1);
    BARRIER();
  }

  // epilogue: row = m0 + mh*128 + wmi*64 + mq*16 + quad*4 + r
  //           col = n0 + nh*128 + wni*32 + nq*16 + q15
  const int rowb = m0 + wmi * 64 + quad * 4;
  const int colb = n0 + wni * 32 + q15;
#pragma unroll
  for (int mh = 0; mh < 2; mh++)
#pragma unroll
    for (int mq = 0; mq < 4; mq++)
#pragma unroll
      for (int nh = 0; nh < 2; nh++)
#pragma unroll
        for (int nq = 0; nq < 2; nq++) {
          const f32x4 av = acc[mh * 4 + mq][nh * 2 + nq];
          const int row = rowb + mh * 128 + mq * 16;
          const int col = colb + nh * 128 + nq * 16;
          if (MODE == 4) {
            if (npart == 2) {          // k projection -> k_buf
              u16* Cout = (u16*)CoutV2;
              const int rk = row - NR;
              const int ck = col - 1536;
#pragma unroll
              for (int r = 0; r < 4; r++)
                Cout[(size_t)(rk + r) * HD + ck] = f2bf(av[r]);
            } else if (npart == 0) {   // q projection, row-major
              u16* Cout = (u16*)CoutV;
#pragma unroll
              for (int r = 0; r < 4; r++)
                Cout[(size_t)(row + r) * HD + col] = f2bf(av[r]);
            } else {                   // v projection, transposed store
              u16* Cout = (u16*)CoutV;
              const int vn = col - HD;
              const int bb = row >> 10;
              const int tl = row & 1023;
              u16x4 pk;
#pragma unroll
              for (int r = 0; r < 4; r++) pk[r] = f2bf(av[r]);
              *(u16x4*)&Cout[(size_t)(NR * HD) + ((size_t)(bb * HD + vn)) * TSEQ + tl] = pk;
            }
          } else {
            if (col < CC) {
              float* Cout = (float*)CoutV;
              const float bvv = bias[col];
#pragma unroll
              for (int r = 0; r < 4; r++)
                Cout[(size_t)(row + r) * CC + col] = av[r] + bvv;
            }
          }
        }
}

// ---------------- flash attention (+T5 setprio; KPW=640 pad) -------------
__global__ __launch_bounds__(256, 3) void attn_kernel(
    const u16* __restrict__ qb, const u16* __restrict__ kb,
    const u16* __restrict__ vt, u16* __restrict__ attn) {
  __shared__ u16 smem[128 * 96 + 64 * 104 + 96 * 72];
  u16* Qs = smem;                       // [128][96]; later aliased by Pt
  u16* Ks = smem + 128 * 96;            // [64][104] pitch-padded
  u16* Vs = smem + 128 * 96 + 64 * 104; // [96][72]  pitch-padded
  u16* Pt = smem;                       // per-wave [32 q][pitch 88]

  const int tid  = threadIdx.x;
  const int lane = tid & 63;
  const int wave = tid >> 6;
  const int q15  = lane & 15;
  const int quad = lane >> 4;
  const int bid  = blockIdx.x;
  const int loc  = bid >> 3;
  const int pair = (bid & 7) * 16 + (loc >> 3);
  const int b  = pair >> 3;
  const int h  = pair & 7;
  const int t0 = (loc & 7) * 128;
  const int wq0 = wave * 32;

  int krow[3], kc[3], vrow[3], vc[3];
#pragma unroll
  for (int p = 0; p < 3; p++) {
    int qk = tid + 256 * p;
    krow[p] = qk / 12; kc[p] = (qk % 12) * 8;
    int qv = tid + 256 * p;
    vrow[p] = qv / 8;  vc[p] = (qv % 8) * 8;
  }
  const u16* kbase = &kb[(size_t)(b * TSEQ) * HD + h * DP];
  const u16* vbase = &vt[(size_t)(b * HD + h * DP) * TSEQ];

  for (int q = tid; q < 128 * 12; q += 256) {
    int row = q / 12, c8 = (q % 12) * 8;
    *(u16x8*)&Qs[row * 96 + c8] =
        *(const u16x8*)&qb[(size_t)(b * TSEQ + t0 + row) * HD + h * DP + c8];
  }
  if (tid < 128) {
    const u16x8 z = {0, 0, 0, 0, 0, 0, 0, 0};
    size_t base = (size_t)(b * TSEQ + t0 + tid) * KPW + CC;
#pragma unroll
    for (int c = 0; c < (KPW - CC) / 8; c++) *(u16x8*)&attn[base + c * 8] = z;
  }
  __syncthreads();

  bf16x8 aq[2][3];
#pragma unroll
  for (int n = 0; n < 2; n++)
#pragma unroll
    for (int kcx = 0; kcx < 3; kcx++)
      aq[n][kcx] = as_bf(*(const u16x8*)&Qs[(wq0 + n * 16 + q15) * 96 + kcx * 32 + quad * 8]);

  float lsum[2] = {0.f, 0.f};
  f32x4 oacc[2][6];
#pragma unroll
  for (int m = 0; m < 2; m++)
#pragma unroll
    for (int jd = 0; jd < 6; jd++) oacc[m][jd] = (f32x4){0.f, 0.f, 0.f, 0.f};

  u16* Ptw = &Pt[wave * 32 * PPITCH];

  u16x8 kreg[3], vreg[3];
#pragma unroll
  for (int p = 0; p < 3; p++) {
    kreg[p] = *(const u16x8*)&kbase[(size_t)krow[p] * HD + kc[p]];
    vreg[p] = *(const u16x8*)&vbase[(size_t)vrow[p] * TSEQ + vc[p]];
  }

  for (int si = 0; si < 16; ++si) {
#pragma unroll
    for (int p = 0; p < 3; p++) {
      *(u16x8*)&Ks[krow[p] * 104 + kc[p]] = kreg[p];
      *(u16x8*)&Vs[vrow[p] * 72 + vc[p]]  = vreg[p];
    }
    __syncthreads();

    if (si < 15) {
      const int s1 = (si + 1) * 64;
#pragma unroll
      for (int p = 0; p < 3; p++) {
        kreg[p] = *(const u16x8*)&kbase[(size_t)(s1 + krow[p]) * HD + kc[p]];
        vreg[p] = *(const u16x8*)&vbase[(size_t)vrow[p] * TSEQ + s1 + vc[p]];
      }
    }

    f32x4 st[4][2];
#pragma unroll
    for (int mt = 0; mt < 4; mt++)
#pragma unroll
      for (int n = 0; n < 2; n++) st[mt][n] = (f32x4){0.f, 0.f, 0.f, 0.f};
    __builtin_amdgcn_s_setprio(1);
#pragma unroll
    for (int kcx = 0; kcx < 3; kcx++) {
      bf16x8 ak[4];
#pragma unroll
      for (int mt = 0; mt < 4; mt++)
        ak[mt] = as_bf(*(const u16x8*)&Ks[(mt * 16 + q15) * 104 + kcx * 32 + quad * 8]);
#pragma unroll
      for (int mt = 0; mt < 4; mt++)
#pragma unroll
        for (int n = 0; n < 2; n++)
          st[mt][n] = __builtin_amdgcn_mfma_f32_16x16x32_bf16(ak[mt], aq[n][kcx], st[mt][n], 0, 0, 0);
    }
    __builtin_amdgcn_s_setprio(0);

#pragma unroll
    for (int mt = 0; mt < 4; mt++)
#pragma unroll
      for (int n = 0; n < 2; n++) {
        f32x4 pv;
#pragma unroll
        for (int r = 0; r < 4; r++) pv[r] = __builtin_amdgcn_exp2f(st[mt][n][r] * CEXP);
        lsum[n] += (pv[0] + pv[1]) + (pv[2] + pv[3]);
        u16x4 pk;
#pragma unroll
        for (int r = 0; r < 4; r++) pk[r] = f2bf(pv[r]);
        *(u16x4*)&Ptw[(n * 16 + q15) * PPITCH + mt * 16 + quad * 4] = pk;
      }

    __builtin_amdgcn_s_setprio(1);
#pragma unroll
    for (int kcx = 0; kcx < 2; kcx++) {
      bf16x8 ap[2];
#pragma unroll
      for (int m = 0; m < 2; m++)
        ap[m] = as_bf(*(const u16x8*)&Ptw[(m * 16 + q15) * PPITCH + kcx * 32 + quad * 8]);
#pragma unroll
      for (int jd = 0; jd < 6; jd++) {
        bf16x8 bv = as_bf(*(const u16x8*)&Vs[(jd * 16 + q15) * 72 + kcx * 32 + quad * 8]);
#pragma unroll
        for (int m = 0; m < 2; m++)
          oacc[m][jd] = __builtin_amdgcn_mfma_f32_16x16x32_bf16(ap[m], bv, oacc[m][jd], 0, 0, 0);
      }
    }
    __builtin_amdgcn_s_setprio(0);
    __syncthreads();
  }

  float lr[2];
#pragma unroll
  for (int n = 0; n < 2; n++) {
    float s = lsum[n];
    s += __shfl_xor(s, 16);
    s += __shfl_xor(s, 32);
    lr[n] = s;
  }

#pragma unroll
  for (int m = 0; m < 2; m++) {
#pragma unroll
    for (int r = 0; r < 4; r++) {
      const float inv = 1.f / __shfl(lr[m], quad * 4 + r);
      const int trow = t0 + wq0 + m * 16 + quad * 4 + r;
#pragma unroll
      for (int jd = 0; jd < 5; jd++) {
        const int d = jd * 16 + q15;
        if (d < DHD)
          attn[(size_t)(b * TSEQ + trow) * KPW + h * DHD + d] = f2bf(oacc[m][jd][r] * inv);
      }
    }
  }
}

// ---------------- launch ----------------

extern "C" void kernel_launch(void* const* d_in, const int* in_sizes, int n_in,
                              void* d_out, int out_size, void* d_ws, size_t ws_size,
                              hipStream_t stream) {
  const float* x   = (const float*)d_in[0];
  const float* mem = (const float*)d_in[1];
  const float* Wq  = (const float*)d_in[2];
  const float* Wk  = (const float*)d_in[3];
  const float* Wv  = (const float*)d_in[4];
  const float* Wp  = (const float*)d_in[5];
  const float* bp  = (const float*)d_in[6];
  float* out = (float*)d_out;

  char* ws = (char*)d_ws;
  const size_t SZ_XMB = (size_t)2 * NR * KPW * 2;  // 41,943,040
  const size_t SZ_WT  = (size_t)3 * HD * KPW * 2;  //  2,949,120 (q|v|k rows)
  const size_t SZ_WPT = (size_t)NP3 * KPW * 2;     //    983,040
  const size_t SZ_QB  = (size_t)NR * HD * 2;       // 25,165,824

  u16* xmb    = (u16*)(ws);            // [32768][640]; dead after projections
  u16* attn_o = (u16*)(ws);            // alias: [16384][640] padded
  u16* wt     = (u16*)(ws + SZ_XMB);
  u16* wp_t   = (u16*)(ws + SZ_XMB + SZ_WT);
  u16* q_buf  = (u16*)(ws + SZ_XMB + SZ_WT + SZ_WPT);       // q then vt contiguous
  u16* vt_buf = q_buf + (size_t)NR * HD;
  u16* k_buf  = (u16*)(ws + SZ_XMB + SZ_WT + SZ_WPT + 2 * SZ_QB);
  // total ws use: 41.9 + 2.9 + 1.0 + 75.5 MB ~= 121.4 MB

  (void)in_sizes; (void)n_in; (void)out_size; (void)ws_size;

  static bool s_attr = false;
  if (!s_attr) {
    (void)hipFuncSetAttribute((const void*)gemm8_kernel<4>,
                              hipFuncAttributeMaxDynamicSharedMemorySize, 131072);
    (void)hipFuncSetAttribute((const void*)gemm8_kernel<2>,
                              hipFuncAttributeMaxDynamicSharedMemorySize, 131072);
    s_attr = true;
  }

  // fused packs
  pack_all_kernel<<<PKA + PKB2 + PKC2, 256, 0, stream>>>(x, mem, Wq, Wk, Wv, Wp,
                                                         xmb, wt, wp_t);

  // all three projections in ONE launch (x rows: q+v; mem rows: k)
  gemm8_kernel<4><<<576, 512, 131072, stream>>>(xmb, wt, q_buf, k_buf, nullptr);

  // attention (writes attn_o with zeroed pad, aliasing dead xmb)
  attn_kernel<<<BB * HH * (TSEQ / 128), 256, 0, stream>>>(q_buf, k_buf, vt_buf, attn_o);

  // output projection + bias -> f32 out (N padded to 768)
  gemm8_kernel<2><<<192, 512, 131072, stream>>>(attn_o, wp_t, out, nullptr, bp);
}

// Round 5
// 289.272 us; speedup vs baseline: 1.0437x; 1.0437x over previous
//
#include <hip/hip_runtime.h>
#include <hip/hip_bf16.h>

typedef unsigned short u16;
typedef __attribute__((ext_vector_type(4))) unsigned short u16x4;
typedef __attribute__((ext_vector_type(8))) unsigned short u16x8;
typedef __attribute__((ext_vector_type(8))) __bf16 bf16x8;
typedef __attribute__((ext_vector_type(4))) float f32x4;

#define BB 16
#define TSEQ 1024
#define CC 584          /* embed dim */
#define HH 8
#define DHD 73
#define NR (BB*TSEQ)    /* 16384 rows */
#define KPW 640         /* padded K: 10 x 64 K-tiles */
#define DP 96           /* padded head dim */
#define HD (HH*DP)      /* 768 */
#define NP3 768         /* padded N for final proj (4 x 192 tiles) */
#define PPITCH 88
/* exp(s*584^-0.5) == exp2(s * CEXP); scores bounded -> no max subtraction */
#define CEXP 0.0596985934f

__device__ __forceinline__ u16 f2bf(float f) {
  __bf16 h = (__bf16)f;                 // native v_cvt, RNE
  return __builtin_bit_cast(u16, h);
}
__device__ __forceinline__ bf16x8 as_bf(u16x8 v) { return __builtin_bit_cast(bf16x8, v); }

/* async global->LDS, 16B/lane, LDS dst = wave-uniform base + lane*16 */
#define GLL16(g, l) __builtin_amdgcn_global_load_lds( \
    (const __attribute__((address_space(1))) void*)(g), \
    (__attribute__((address_space(3))) void*)(l), 16, 0, 0)

#define BARRIER() asm volatile("s_barrier" ::: "memory")
#define VMW7()    asm volatile("s_waitcnt vmcnt(7)" ::: "memory")
#define VMW2()    asm volatile("s_waitcnt vmcnt(2)" ::: "memory")
#define VMW0()    asm volatile("s_waitcnt vmcnt(0)" ::: "memory")

// ---------------- fused pack kernel ----------------
// phase A (10240 blocks): x|mem [16384,584] f32 -> xmb [32768][640] bf16 zero-pad
// phase B (720 blocks x 2048 elems):  Wq/Wv/Wk -> wt [q|v|k 768 rows][640] bf16
// phase C (240 blocks x 2048 elems):  Wp -> wpt [768][640] bf16 (transposed)
#define PKA 10240
#define PKB2 720
#define PKC2 240
__global__ void pack_all_kernel(const float* __restrict__ x, const float* __restrict__ mem,
                                const float* __restrict__ Wq, const float* __restrict__ Wk,
                                const float* __restrict__ Wv, const float* __restrict__ Wp,
                                u16* __restrict__ xmb, u16* __restrict__ wt,
                                u16* __restrict__ wpt) {
  const int bidx = blockIdx.x;
  const int tid = threadIdx.x;
  if (bidx < PKA) {
    int idx = bidx * 256 + tid;
    int row = idx / (KPW / 8);
    int c8  = (idx % (KPW / 8)) * 8;
    u16x8 o = {0, 0, 0, 0, 0, 0, 0, 0};
    if (c8 < CC) {
      const float* src = (row < NR) ? &x[(size_t)row * CC + c8]
                                    : &mem[(size_t)(row - NR) * CC + c8];
      f32x4 a = *(const f32x4*)src;
      f32x4 b = *(const f32x4*)(src + 4);
#pragma unroll
      for (int t = 0; t < 4; t++) { o[t] = f2bf(a[t]); o[4 + t] = f2bf(b[t]); }
    }
    *(u16x8*)&xmb[(size_t)row * KPW + c8] = o;
  } else if (bidx < PKA + PKB2) {
    const int base = (bidx - PKA) * 2048 + tid;
#pragma unroll
    for (int e = 0; e < 8; e++) {
      int idx = base + e * 256;
      int w   = idx / (HD * KPW);
      int rem = idx % (HD * KPW);
      int n = rem / KPW;
      int k = rem % KPW;
      int h = n / DP, d = n % DP;
      u16 val = 0;
      if (d < DHD && k < CC) {
        const float* W = (w == 0) ? Wq : ((w == 1) ? Wv : Wk);  // order: q, v, k
        val = f2bf(W[((size_t)h * CC + k) * DHD + d]);
      }
      wt[idx] = val;
    }
  } else {
    const int base = (bidx - PKA - PKB2) * 2048 + tid;
#pragma unroll
    for (int e = 0; e < 8; e++) {
      int idx = base + e * 256;
      int n = idx / KPW;
      int c = idx % KPW;
      u16 val = 0;
      if (n < CC && c < CC) val = f2bf(Wp[(size_t)c * CC + n]);
      wpt[idx] = val;
    }
  }
}

// ---------------- 256x192 GEMM, 2-phase/K-tile, exact CU rounds ----------------
// 512 threads = 8 waves (2M x 4N); wave owns rows mh*128 + wmi*64 + [0,64)
// (mh phase-iterated), cols wni*48 + [0,48). BN=192 makes gemm<4> grid 768 =
// exactly 3 rounds of 256 CUs and gemm<2> 256 = 1 round (removes the 2.25-round
// makespan quantization of BN=256).
// LDS: 2 bufs x (A[256][64] + B[192][64]) bf16 = 112 KB. Per K-tile t (buf=t&1):
//   ph_a: rd A-mh0 (8 b128) + rd B all (6 b128); stage S_A1(t+1 -> buf^1) [2];
//         vmcnt(7); barrier; 24 MFMA (setprio-wrapped); barrier
//   ph_b: rd A-mh1 (8); stage S_A0B(t+2 -> buf) [5]; vmcnt(7); barrier;
//         24 MFMA (B frags reused); barrier
// Retire proof: ph_a(t) outstanding after issue = (t).A1[2]+(t+1).A0B[5]+
// (t+1).A1[2] = 9 -> vmcnt(7) retires (t).A1 (read ph_b(t)). ph_b(t): (t+1)[7]
// +(t+2).A0B[5] = 12 -> vmcnt(7) retires (t+1).A0B (read ph_a(t+1)). Regions
// overwritten only >=1 barrier after last read. Tails: ph_b(8) vmcnt(2),
// ph_a(9) vmcnt(0). No manual lgkmcnt: ds_reads are C++ loads, compiler
// emits counted lgkm waits. T2 swizzle (pre-swizzled global src + XOR read)
// kept: 0 bank conflicts (verified r1).

__device__ __forceinline__ void rd_a3(bf16x8 (&a)[4][2], const u16* lds, int base,
                                      int sw0, int sw1) {
#pragma unroll
  for (int mq = 0; mq < 4; mq++) {
    const int r = base + mq * 1024;
    a[mq][0] = as_bf(*(const u16x8*)&lds[r + sw0]);
    a[mq][1] = as_bf(*(const u16x8*)&lds[r + sw1]);
  }
}
__device__ __forceinline__ void rd_b3(bf16x8 (&b)[3][2], const u16* lds, int base,
                                      int sw0, int sw1) {
#pragma unroll
  for (int nq = 0; nq < 3; nq++) {
    const int r = base + nq * 1024;
    b[nq][0] = as_bf(*(const u16x8*)&lds[r + sw0]);
    b[nq][1] = as_bf(*(const u16x8*)&lds[r + sw1]);
  }
}
// stage bursts: A1 = A rows 128-255 (2 loads); A0B = A rows 0-127 + B rows 0-191 (5)
__device__ __forceinline__ void s_a1(const u16* gA, u16* ldst, int t, int lb) {
  GLL16(gA + (size_t)128 * KPW + (size_t)t * 64, ldst + lb + 8192);
  GLL16(gA + (size_t)192 * KPW + (size_t)t * 64, ldst + lb + 12288);
}
__device__ __forceinline__ void s_a0b(const u16* gA, const u16* gB, u16* ldst,
                                      int t, int lb) {
  GLL16(gA + (size_t)t * 64, ldst + lb);
  GLL16(gA + (size_t)64 * KPW + (size_t)t * 64, ldst + lb + 4096);
  GLL16(gB + (size_t)t * 64, ldst + lb + 16384);
  GLL16(gB + (size_t)64 * KPW + (size_t)t * 64, ldst + lb + 20480);
  GLL16(gB + (size_t)128 * KPW + (size_t)t * 64, ldst + lb + 24576);
}
__device__ __forceinline__ void mm43(f32x4 (&acc)[4][3], const bf16x8 (&a)[4][2],
                                     const bf16x8 (&b)[3][2]) {
  __builtin_amdgcn_s_setprio(1);
#pragma unroll
  for (int mq = 0; mq < 4; mq++)
#pragma unroll
    for (int nq = 0; nq < 3; nq++) {
      f32x4 c = acc[mq][nq];
      c = __builtin_amdgcn_mfma_f32_16x16x32_bf16(a[mq][0], b[nq][0], c, 0, 0, 0);
      c = __builtin_amdgcn_mfma_f32_16x16x32_bf16(a[mq][1], b[nq][1], c, 0, 0, 0);
      acc[mq][nq] = c;
    }
  __builtin_amdgcn_s_setprio(0);
}

// MODE 4: merged projections. A = xmb [32768][640].
//   bid 0..511:  x rows, wt cols 0..1535 (nt<4: q row-major; nt>=4: v transposed)
//   bid 512..767: mem rows, wt cols 1536..2303 (k row-major)
// MODE 2: A = attn [16384][640], Bt = wpt [768][640]; f32 out + bias, col<584.
template <int MODE>
__global__ __launch_bounds__(512, 2) void gemm8_kernel(
    const u16* __restrict__ A, const u16* __restrict__ Bt,
    void* __restrict__ CoutV, void* __restrict__ CoutV2,
    const float* __restrict__ bias) {
  extern __shared__ u16 lds[];
  const int tid  = threadIdx.x;
  const int lane = tid & 63;
  const int q15  = lane & 15;
  const int quad = lane >> 4;
  const int wave = tid >> 6;
  const int wmi  = wave >> 2;     // 0..1
  const int wni  = wave & 3;      // 0..3

  // XCD-contiguous swizzle (grid % 8 == 0 for both modes)
  const int cpx = gridDim.x >> 3;
  const int bid = (blockIdx.x & 7) * cpx + (blockIdx.x >> 3);

  int m0, n0, npart;  // npart: 0=q 1=v 2=k (MODE4)
  if (MODE == 4) {
    if (bid < 512) {
      m0 = (bid >> 3) * 256; int nt = bid & 7;
      n0 = nt * 192; npart = (nt >= 4) ? 1 : 0;
    } else {
      int b2 = bid - 512;
      m0 = NR + (b2 >> 2) * 256; n0 = 1536 + (b2 & 3) * 192; npart = 2;
    }
  } else {
    m0 = (bid >> 2) * 256; n0 = (bid & 3) * 192; npart = 0;
  }

  // staging geometry: thread t covers (row = t>>3, chunk = t&7) of a 64-row unit;
  // source chunk pre-swizzled so swizzled ds_read finds linear data (T2 rule 21).
  const int tr   = tid >> 3;
  const int scol = ((tid & 7) ^ (tr & 7)) * 8;
  const u16* gA = &A[(size_t)(m0 + tr) * KPW + scol];
  const u16* gB = &Bt[(size_t)(n0 + tr) * KPW + scol];
  u16* ldst = &lds[tid * 8];

  // fragment-read swizzled 16B-slot offsets (frag row & 7 == q15 & 7)
  const int rb  = q15 & 7;
  const int sw0 = (quad ^ rb) * 8;
  const int sw1 = ((quad + 4) ^ rb) * 8;
  const int arow = (wmi * 64 + q15) * 64;          // within A half (128 rows)
  const int brow = (wni * 48 + q15) * 64;          // within B (192 rows)

  f32x4 acc[2][4][3];
#pragma unroll
  for (int i = 0; i < 2; i++)
#pragma unroll
    for (int j = 0; j < 4; j++)
#pragma unroll
      for (int k = 0; k < 3; k++) acc[i][j][k] = (f32x4){0.f, 0.f, 0.f, 0.f};
  bf16x8 a[4][2], b[3][2];

  // prologue: (0).A0B, (0).A1, (1).A0B = 12 loads; vmcnt(7) retires (0).A0B
  s_a0b(gA, gB, ldst, 0, 0);
  s_a1(gA, ldst, 0, 0);
  s_a0b(gA, gB, ldst, 1, 28672);
  VMW7(); BARRIER();

#pragma unroll 1
  for (int t = 0; t < 10; ++t) {
    const int lb = (t & 1) * 28672;
    const int lbo = lb ^ 28672;
    // ph_a: compute (mh=0); B read once for both phases
    rd_a3(a, lds, lb + arow, sw0, sw1);
    rd_b3(b, lds, lb + 16384 + brow, sw0, sw1);
    if (t < 9) s_a1(gA, ldst, t + 1, lbo);
    if (t == 9) { VMW0(); } else { VMW7(); }
    BARRIER();
    mm43(acc[0], a, b);
    BARRIER();
    // ph_b: compute (mh=1)
    rd_a3(a, lds, lb + 8192 + arow, sw0, sw1);
    if (t < 8) { s_a0b(gA, gB, ldst, t + 2, lb); VMW7(); }
    else if (t == 8) { VMW2(); }
    BARRIER();
    mm43(acc[1], a, b);
    BARRIER();
  }

  // epilogue: row = m0 + mh*128 + wmi*64 + mq*16 + quad*4 + r
  //           col = n0 + wni*48 + nq*16 + q15
  const int rowb = m0 + wmi * 64 + quad * 4;
  const int colb = n0 + wni * 48 + q15;
#pragma unroll
  for (int mh = 0; mh < 2; mh++)
#pragma unroll
    for (int mq = 0; mq < 4; mq++)
#pragma unroll
      for (int nq = 0; nq < 3; nq++) {
        const f32x4 av = acc[mh][mq][nq];
        const int row = rowb + mh * 128 + mq * 16;
        const int col = colb + nq * 16;
        if (MODE == 4) {
          if (npart == 2) {          // k projection -> k_buf
            u16* Cout = (u16*)CoutV2;
            const int rk = row - NR;
            const int ck = col - 1536;
#pragma unroll
            for (int r = 0; r < 4; r++)
              Cout[(size_t)(rk + r) * HD + ck] = f2bf(av[r]);
          } else if (npart == 0) {   // q projection, row-major
            u16* Cout = (u16*)CoutV;
#pragma unroll
            for (int r = 0; r < 4; r++)
              Cout[(size_t)(row + r) * HD + col] = f2bf(av[r]);
          } else {                   // v projection, transposed store
            u16* Cout = (u16*)CoutV;
            const int vn = col - HD;
            const int bb = row >> 10;
            const int tl = row & 1023;
            u16x4 pk;
#pragma unroll
            for (int r = 0; r < 4; r++) pk[r] = f2bf(av[r]);
            *(u16x4*)&Cout[(size_t)(NR * HD) + ((size_t)(bb * HD + vn)) * TSEQ + tl] = pk;
          }
        } else {
          if (col < CC) {
            float* Cout = (float*)CoutV;
            const float bvv = bias[col];
#pragma unroll
            for (int r = 0; r < 4; r++)
              Cout[(size_t)(row + r) * CC + col] = av[r] + bvv;
          }
        }
      }
}

// ---------------- flash attention (r3 version: NO setprio; KPW=640 pad) -------
__global__ __launch_bounds__(256, 3) void attn_kernel(
    const u16* __restrict__ qb, const u16* __restrict__ kb,
    const u16* __restrict__ vt, u16* __restrict__ attn) {
  __shared__ u16 smem[128 * 96 + 64 * 104 + 96 * 72];
  u16* Qs = smem;                       // [128][96]; later aliased by Pt
  u16* Ks = smem + 128 * 96;            // [64][104] pitch-padded
  u16* Vs = smem + 128 * 96 + 64 * 104; // [96][72]  pitch-padded
  u16* Pt = smem;                       // per-wave [32 q][pitch 88]

  const int tid  = threadIdx.x;
  const int lane = tid & 63;
  const int wave = tid >> 6;
  const int q15  = lane & 15;
  const int quad = lane >> 4;
  const int bid  = blockIdx.x;
  const int loc  = bid >> 3;
  const int pair = (bid & 7) * 16 + (loc >> 3);
  const int b  = pair >> 3;
  const int h  = pair & 7;
  const int t0 = (loc & 7) * 128;
  const int wq0 = wave * 32;

  int krow[3], kc[3], vrow[3], vc[3];
#pragma unroll
  for (int p = 0; p < 3; p++) {
    int qk = tid + 256 * p;
    krow[p] = qk / 12; kc[p] = (qk % 12) * 8;
    int qv = tid + 256 * p;
    vrow[p] = qv / 8;  vc[p] = (qv % 8) * 8;
  }
  const u16* kbase = &kb[(size_t)(b * TSEQ) * HD + h * DP];
  const u16* vbase = &vt[(size_t)(b * HD + h * DP) * TSEQ];

  for (int q = tid; q < 128 * 12; q += 256) {
    int row = q / 12, c8 = (q % 12) * 8;
    *(u16x8*)&Qs[row * 96 + c8] =
        *(const u16x8*)&qb[(size_t)(b * TSEQ + t0 + row) * HD + h * DP + c8];
  }
  if (tid < 128) {
    const u16x8 z = {0, 0, 0, 0, 0, 0, 0, 0};
    size_t base = (size_t)(b * TSEQ + t0 + tid) * KPW + CC;
#pragma unroll
    for (int c = 0; c < (KPW - CC) / 8; c++) *(u16x8*)&attn[base + c * 8] = z;
  }
  __syncthreads();

  bf16x8 aq[2][3];
#pragma unroll
  for (int n = 0; n < 2; n++)
#pragma unroll
    for (int kcx = 0; kcx < 3; kcx++)
      aq[n][kcx] = as_bf(*(const u16x8*)&Qs[(wq0 + n * 16 + q15) * 96 + kcx * 32 + quad * 8]);

  float lsum[2] = {0.f, 0.f};
  f32x4 oacc[2][6];
#pragma unroll
  for (int m = 0; m < 2; m++)
#pragma unroll
    for (int jd = 0; jd < 6; jd++) oacc[m][jd] = (f32x4){0.f, 0.f, 0.f, 0.f};

  u16* Ptw = &Pt[wave * 32 * PPITCH];

  u16x8 kreg[3], vreg[3];
#pragma unroll
  for (int p = 0; p < 3; p++) {
    kreg[p] = *(const u16x8*)&kbase[(size_t)krow[p] * HD + kc[p]];
    vreg[p] = *(const u16x8*)&vbase[(size_t)vrow[p] * TSEQ + vc[p]];
  }

  for (int si = 0; si < 16; ++si) {
#pragma unroll
    for (int p = 0; p < 3; p++) {
      *(u16x8*)&Ks[krow[p] * 104 + kc[p]] = kreg[p];
      *(u16x8*)&Vs[vrow[p] * 72 + vc[p]]  = vreg[p];
    }
    __syncthreads();

    if (si < 15) {
      const int s1 = (si + 1) * 64;
#pragma unroll
      for (int p = 0; p < 3; p++) {
        kreg[p] = *(const u16x8*)&kbase[(size_t)(s1 + krow[p]) * HD + kc[p]];
        vreg[p] = *(const u16x8*)&vbase[(size_t)vrow[p] * TSEQ + s1 + vc[p]];
      }
    }

    f32x4 st[4][2];
#pragma unroll
    for (int mt = 0; mt < 4; mt++)
#pragma unroll
      for (int n = 0; n < 2; n++) st[mt][n] = (f32x4){0.f, 0.f, 0.f, 0.f};
#pragma unroll
    for (int kcx = 0; kcx < 3; kcx++) {
      bf16x8 ak[4];
#pragma unroll
      for (int mt = 0; mt < 4; mt++)
        ak[mt] = as_bf(*(const u16x8*)&Ks[(mt * 16 + q15) * 104 + kcx * 32 + quad * 8]);
#pragma unroll
      for (int mt = 0; mt < 4; mt++)
#pragma unroll
        for (int n = 0; n < 2; n++)
          st[mt][n] = __builtin_amdgcn_mfma_f32_16x16x32_bf16(ak[mt], aq[n][kcx], st[mt][n], 0, 0, 0);
    }

#pragma unroll
    for (int mt = 0; mt < 4; mt++)
#pragma unroll
      for (int n = 0; n < 2; n++) {
        f32x4 pv;
#pragma unroll
        for (int r = 0; r < 4; r++) pv[r] = __builtin_amdgcn_exp2f(st[mt][n][r] * CEXP);
        lsum[n] += (pv[0] + pv[1]) + (pv[2] + pv[3]);
        u16x4 pk;
#pragma unroll
        for (int r = 0; r < 4; r++) pk[r] = f2bf(pv[r]);
        *(u16x4*)&Ptw[(n * 16 + q15) * PPITCH + mt * 16 + quad * 4] = pk;
      }

#pragma unroll
    for (int kcx = 0; kcx < 2; kcx++) {
      bf16x8 ap[2];
#pragma unroll
      for (int m = 0; m < 2; m++)
        ap[m] = as_bf(*(const u16x8*)&Ptw[(m * 16 + q15) * PPITCH + kcx * 32 + quad * 8]);
#pragma unroll
      for (int jd = 0; jd < 6; jd++) {
        bf16x8 bv = as_bf(*(const u16x8*)&Vs[(jd * 16 + q15) * 72 + kcx * 32 + quad * 8]);
#pragma unroll
        for (int m = 0; m < 2; m++)
          oacc[m][jd] = __builtin_amdgcn_mfma_f32_16x16x32_bf16(ap[m], bv, oacc[m][jd], 0, 0, 0);
      }
    }
    __syncthreads();
  }

  float lr[2];
#pragma unroll
  for (int n = 0; n < 2; n++) {
    float s = lsum[n];
    s += __shfl_xor(s, 16);
    s += __shfl_xor(s, 32);
    lr[n] = s;
  }

#pragma unroll
  for (int m = 0; m < 2; m++) {
#pragma unroll
    for (int r = 0; r < 4; r++) {
      const float inv = 1.f / __shfl(lr[m], quad * 4 + r);
      const int trow = t0 + wq0 + m * 16 + quad * 4 + r;
#pragma unroll
      for (int jd = 0; jd < 5; jd++) {
        const int d = jd * 16 + q15;
        if (d < DHD)
          attn[(size_t)(b * TSEQ + trow) * KPW + h * DHD + d] = f2bf(oacc[m][jd][r] * inv);
      }
    }
  }
}

// ---------------- launch ----------------

extern "C" void kernel_launch(void* const* d_in, const int* in_sizes, int n_in,
                              void* d_out, int out_size, void* d_ws, size_t ws_size,
                              hipStream_t stream) {
  const float* x   = (const float*)d_in[0];
  const float* mem = (const float*)d_in[1];
  const float* Wq  = (const float*)d_in[2];
  const float* Wk  = (const float*)d_in[3];
  const float* Wv  = (const float*)d_in[4];
  const float* Wp  = (const float*)d_in[5];
  const float* bp  = (const float*)d_in[6];
  float* out = (float*)d_out;

  char* ws = (char*)d_ws;
  const size_t SZ_XMB = (size_t)2 * NR * KPW * 2;  // 41,943,040
  const size_t SZ_WT  = (size_t)3 * HD * KPW * 2;  //  2,949,120 (q|v|k rows)
  const size_t SZ_WPT = (size_t)NP3 * KPW * 2;     //    983,040
  const size_t SZ_QB  = (size_t)NR * HD * 2;       // 25,165,824

  u16* xmb    = (u16*)(ws);            // [32768][640]; dead after projections
  u16* attn_o = (u16*)(ws);            // alias: [16384][640] padded
  u16* wt     = (u16*)(ws + SZ_XMB);
  u16* wp_t   = (u16*)(ws + SZ_XMB + SZ_WT);
  u16* q_buf  = (u16*)(ws + SZ_XMB + SZ_WT + SZ_WPT);       // q then vt contiguous
  u16* vt_buf = q_buf + (size_t)NR * HD;
  u16* k_buf  = (u16*)(ws + SZ_XMB + SZ_WT + SZ_WPT + 2 * SZ_QB);
  // total ws use: 41.9 + 2.9 + 1.0 + 75.5 MB ~= 121.4 MB

  (void)in_sizes; (void)n_in; (void)out_size; (void)ws_size;

  static bool s_attr = false;
  if (!s_attr) {
    (void)hipFuncSetAttribute((const void*)gemm8_kernel<4>,
                              hipFuncAttributeMaxDynamicSharedMemorySize, 114688);
    (void)hipFuncSetAttribute((const void*)gemm8_kernel<2>,
                              hipFuncAttributeMaxDynamicSharedMemorySize, 114688);
    s_attr = true;
  }

  // fused packs
  pack_all_kernel<<<PKA + PKB2 + PKC2, 256, 0, stream>>>(x, mem, Wq, Wk, Wv, Wp,
                                                         xmb, wt, wp_t);

  // all three projections in ONE launch; 768 blocks = exactly 3 CU rounds
  gemm8_kernel<4><<<768, 512, 114688, stream>>>(xmb, wt, q_buf, k_buf, nullptr);

  // attention (writes attn_o with zeroed pad, aliasing dead xmb)
  attn_kernel<<<BB * HH * (TSEQ / 128), 256, 0, stream>>>(q_buf, k_buf, vt_buf, attn_o);

  // output projection + bias -> f32 out; 256 blocks = exactly 1 CU round
  gemm8_kernel<2><<<256, 512, 114688, stream>>>(attn_o, wp_t, out, nullptr, bp);
}

// Round 6
// 286.906 us; speedup vs baseline: 1.0523x; 1.0082x over previous
//
#include <hip/hip_runtime.h>
#include <hip/hip_bf16.h>

typedef unsigned short u16;
typedef __attribute__((ext_vector_type(4))) unsigned short u16x4;
typedef __attribute__((ext_vector_type(8))) unsigned short u16x8;
typedef __attribute__((ext_vector_type(8))) __bf16 bf16x8;
typedef __attribute__((ext_vector_type(4))) float f32x4;

#define BB 16
#define TSEQ 1024
#define CC 584          /* embed dim */
#define HH 8
#define DHD 73
#define NR (BB*TSEQ)    /* 16384 rows */
#define KPW 640         /* padded K: 10 x 64 K-tiles */
#define DP 80           /* padded head dim (73 -> 80 = 5x16) */
#define HD (HH*DP)      /* 640 */
#define NP3 768         /* padded N for final proj (4 x 192 tiles) */
#define PPITCH 88
/* exp(s*584^-0.5) == exp2(s * CEXP); scores bounded -> no max subtraction */
#define CEXP 0.0596985934f

__device__ __forceinline__ u16 f2bf(float f) {
  __bf16 h = (__bf16)f;                 // native v_cvt, RNE
  return __builtin_bit_cast(u16, h);
}
__device__ __forceinline__ bf16x8 as_bf(u16x8 v) { return __builtin_bit_cast(bf16x8, v); }

/* async global->LDS, 16B/lane, LDS dst = wave-uniform base + lane*16 */
#define GLL16(g, l) __builtin_amdgcn_global_load_lds( \
    (const __attribute__((address_space(1))) void*)(g), \
    (__attribute__((address_space(3))) void*)(l), 16, 0, 0)

#define BARRIER() asm volatile("s_barrier" ::: "memory")
#define VMW7()    asm volatile("s_waitcnt vmcnt(7)" ::: "memory")
#define VMW6()    asm volatile("s_waitcnt vmcnt(6)" ::: "memory")
#define VMW2()    asm volatile("s_waitcnt vmcnt(2)" ::: "memory")
#define VMW0()    asm volatile("s_waitcnt vmcnt(0)" ::: "memory")

// ---------------- fused pack kernel ----------------
// phase A (10240 blocks): x|mem [16384,584] f32 -> xmb [32768][640] bf16 zero-pad
// phase B (600 blocks x 2048): Wq/Wv/Wk -> wt [q 640 | v 640 | k 640 rows][640]
// phase C (240 blocks x 2048): Wp -> wpt [768][640] bf16 (transposed)
#define PKA 10240
#define PKB2 600
#define PKC2 240
__global__ void pack_all_kernel(const float* __restrict__ x, const float* __restrict__ mem,
                                const float* __restrict__ Wq, const float* __restrict__ Wk,
                                const float* __restrict__ Wv, const float* __restrict__ Wp,
                                u16* __restrict__ xmb, u16* __restrict__ wt,
                                u16* __restrict__ wpt) {
  const int bidx = blockIdx.x;
  const int tid = threadIdx.x;
  if (bidx < PKA) {
    int idx = bidx * 256 + tid;
    int row = idx / (KPW / 8);
    int c8  = (idx % (KPW / 8)) * 8;
    u16x8 o = {0, 0, 0, 0, 0, 0, 0, 0};
    if (c8 < CC) {
      const float* src = (row < NR) ? &x[(size_t)row * CC + c8]
                                    : &mem[(size_t)(row - NR) * CC + c8];
      f32x4 a = *(const f32x4*)src;
      f32x4 b = *(const f32x4*)(src + 4);
#pragma unroll
      for (int t = 0; t < 4; t++) { o[t] = f2bf(a[t]); o[4 + t] = f2bf(b[t]); }
    }
    *(u16x8*)&xmb[(size_t)row * KPW + c8] = o;
  } else if (bidx < PKA + PKB2) {
    const int base = (bidx - PKA) * 2048 + tid;
#pragma unroll
    for (int e = 0; e < 8; e++) {
      int idx = base + e * 256;
      int w   = idx / (HD * KPW);
      int rem = idx % (HD * KPW);
      int n = rem / KPW;
      int k = rem % KPW;
      int h = n / DP, d = n % DP;
      u16 val = 0;
      if (d < DHD && k < CC) {
        const float* W = (w == 0) ? Wq : ((w == 1) ? Wv : Wk);  // order: q, v, k
        val = f2bf(W[((size_t)h * CC + k) * DHD + d]);
      }
      wt[idx] = val;
    }
  } else {
    const int base = (bidx - PKA - PKB2) * 2048 + tid;
#pragma unroll
    for (int e = 0; e < 8; e++) {
      int idx = base + e * 256;
      int n = idx / KPW;
      int c = idx % KPW;
      u16 val = 0;
      if (n < CC && c < CC) val = f2bf(Wp[(size_t)c * CC + n]);
      wpt[idx] = val;
    }
  }
}

// ---------------- 256xBN GEMM, 2-phase/K-tile (r5-proven schedule) ----------------
// MODE4: BN=128 (NB=2 B-units). wt has 1920 rows (DP=80): grid 960.
// MODE2: BN=192 (NB=3). grid 256 = 1 round (r5 exact config).
// Per K-tile t (buf=t&1):
//   ph_a: rd A-mh0 (8 b128) + rd B all (2*NQ b128); stage S_A1(t+1 -> buf^1)[2];
//         vmcnt(4+NB); barrier; MFMA; barrier
//   ph_b: rd A-mh1 (8); stage S_A0B(t+2 -> buf)[2+NB]; vmcnt(4+NB); barrier;
//         MFMA (B frags reused); barrier
// Retire proof (generalized r5): ph_a outstanding = 2+(2+NB)+2 = 6+NB ->
// vmcnt(4+NB) retires A1(t). ph_b outstanding = (4+NB)+(2+NB) -> retires
// A0B(t+1). Tails: t=8 ph_b vmcnt(2); t=9 ph_a vmcnt(0). T2 swizzle kept
// (pre-swizzled global src + XOR read): 0 bank conflicts (verified r1).

__device__ __forceinline__ void rd_a4(bf16x8 (&a)[4][2], const u16* lds, int base,
                                      int sw0, int sw1) {
#pragma unroll
  for (int mq = 0; mq < 4; mq++) {
    const int r = base + mq * 1024;
    a[mq][0] = as_bf(*(const u16x8*)&lds[r + sw0]);
    a[mq][1] = as_bf(*(const u16x8*)&lds[r + sw1]);
  }
}
template <int NQ>
__device__ __forceinline__ void rd_bn(bf16x8 (&b)[NQ][2], const u16* lds, int base,
                                      int sw0, int sw1) {
#pragma unroll
  for (int nq = 0; nq < NQ; nq++) {
    const int r = base + nq * 1024;
    b[nq][0] = as_bf(*(const u16x8*)&lds[r + sw0]);
    b[nq][1] = as_bf(*(const u16x8*)&lds[r + sw1]);
  }
}
__device__ __forceinline__ void s_a1(const u16* gA, u16* ldst, int t, int lb) {
  GLL16(gA + (size_t)128 * KPW + (size_t)t * 64, ldst + lb + 8192);
  GLL16(gA + (size_t)192 * KPW + (size_t)t * 64, ldst + lb + 12288);
}
template <int NB>
__device__ __forceinline__ void s_a0b(const u16* gA, const u16* gB, u16* ldst,
                                      int t, int lb) {
  GLL16(gA + (size_t)t * 64, ldst + lb);
  GLL16(gA + (size_t)64 * KPW + (size_t)t * 64, ldst + lb + 4096);
#pragma unroll
  for (int u = 0; u < NB; u++)
    GLL16(gB + (size_t)(u * 64) * KPW + (size_t)t * 64, ldst + lb + 16384 + u * 4096);
}
template <int NQ>
__device__ __forceinline__ void mm4n(f32x4 (&acc)[4][NQ], const bf16x8 (&a)[4][2],
                                     const bf16x8 (&b)[NQ][2]) {
  __builtin_amdgcn_s_setprio(1);
#pragma unroll
  for (int mq = 0; mq < 4; mq++)
#pragma unroll
    for (int nq = 0; nq < NQ; nq++) {
      f32x4 c = acc[mq][nq];
      c = __builtin_amdgcn_mfma_f32_16x16x32_bf16(a[mq][0], b[nq][0], c, 0, 0, 0);
      c = __builtin_amdgcn_mfma_f32_16x16x32_bf16(a[mq][1], b[nq][1], c, 0, 0, 0);
      acc[mq][nq] = c;
    }
  __builtin_amdgcn_s_setprio(0);
}

// MODE 4: A = xmb [32768][640]; bid<640: x rows (nt<5 q n0=nt*128; else v);
//   bid>=640: mem rows, k cols 1280..1919.
// MODE 2: A = attn [16384][640], Bt = wpt [768][640]; f32 out + bias, col<584.
template <int MODE>
__global__ __launch_bounds__(512, 2) void gemm8_kernel(
    const u16* __restrict__ A, const u16* __restrict__ Bt,
    void* __restrict__ CoutV, void* __restrict__ CoutV2,
    const float* __restrict__ bias) {
  constexpr int NB = (MODE == 4) ? 2 : 3;   // B 64-row units
  constexpr int NQ = NB;                    // n-frags per wave (32 or 48 cols)
  constexpr int WN = NQ * 16;
  constexpr int SB = 16384 + NB * 4096;     // LDS buf stride (u16)
  extern __shared__ u16 lds[];
  const int tid  = threadIdx.x;
  const int lane = tid & 63;
  const int q15  = lane & 15;
  const int quad = lane >> 4;
  const int wave = tid >> 6;
  const int wmi  = wave >> 2;     // 0..1
  const int wni  = wave & 3;      // 0..3

  // XCD-contiguous swizzle (grid % 8 == 0 for both modes)
  const int cpx = gridDim.x >> 3;
  const int bid = (blockIdx.x & 7) * cpx + (blockIdx.x >> 3);

  int m0, n0, npart;  // npart: 0=q 1=v 2=k (MODE4)
  if (MODE == 4) {
    if (bid < 640) {
      m0 = (bid / 10) * 256; int nt = bid % 10;
      if (nt < 5) { n0 = nt * 128; npart = 0; }
      else        { n0 = 640 + (nt - 5) * 128; npart = 1; }
    } else {
      int b2 = bid - 640;
      m0 = NR + (b2 / 5) * 256; n0 = 1280 + (b2 % 5) * 128; npart = 2;
    }
  } else {
    m0 = (bid >> 2) * 256; n0 = (bid & 3) * 192; npart = 0;
  }

  // staging geometry: thread t covers (row = t>>3, chunk = t&7) of a 64-row unit;
  // source chunk pre-swizzled so swizzled ds_read finds linear data (T2 rule 21).
  const int tr   = tid >> 3;
  const int scol = ((tid & 7) ^ (tr & 7)) * 8;
  const u16* gA = &A[(size_t)(m0 + tr) * KPW + scol];
  const u16* gB = &Bt[(size_t)(n0 + tr) * KPW + scol];
  u16* ldst = &lds[tid * 8];

  // fragment-read swizzled 16B-slot offsets (frag row & 7 == q15 & 7)
  const int rb  = q15 & 7;
  const int sw0 = (quad ^ rb) * 8;
  const int sw1 = ((quad + 4) ^ rb) * 8;
  const int arow = (wmi * 64 + q15) * 64;          // within A half (128 rows)
  const int brow = (wni * WN + q15) * 64;          // within B (BN rows)

  f32x4 acc[2][4][NQ];
#pragma unroll
  for (int i = 0; i < 2; i++)
#pragma unroll
    for (int j = 0; j < 4; j++)
#pragma unroll
      for (int k = 0; k < NQ; k++) acc[i][j][k] = (f32x4){0.f, 0.f, 0.f, 0.f};
  bf16x8 a[4][2], b[NQ][2];

  // prologue: (0).A0B, (0).A1, (1).A0B; vmcnt(4+NB) retires (0).A0B
  s_a0b<NB>(gA, gB, ldst, 0, 0);
  s_a1(gA, ldst, 0, 0);
  s_a0b<NB>(gA, gB, ldst, 1, SB);
  if constexpr (NB == 2) VMW6(); else VMW7();
  BARRIER();

#pragma unroll 1
  for (int t = 0; t < 10; ++t) {
    const int lb = (t & 1) * SB;
    const int lbo = lb ^ SB;
    // ph_a: compute (mh=0); B read once for both phases
    rd_a4(a, lds, lb + arow, sw0, sw1);
    rd_bn<NQ>(b, lds, lb + 16384 + brow, sw0, sw1);
    if (t < 9) s_a1(gA, ldst, t + 1, lbo);
    if (t == 9) { VMW0(); } else { if constexpr (NB == 2) VMW6(); else VMW7(); }
    BARRIER();
    mm4n<NQ>(acc[0], a, b);
    BARRIER();
    // ph_b: compute (mh=1)
    rd_a4(a, lds, lb + 8192 + arow, sw0, sw1);
    if (t < 8) { s_a0b<NB>(gA, gB, ldst, t + 2, lb);
                 if constexpr (NB == 2) VMW6(); else VMW7(); }
    else if (t == 8) { VMW2(); }
    BARRIER();
    mm4n<NQ>(acc[1], a, b);
    BARRIER();
  }

  // epilogue: row = m0 + mh*128 + wmi*64 + mq*16 + quad*4 + r
  //           col = n0 + wni*WN + nq*16 + q15
  const int rowb = m0 + wmi * 64 + quad * 4;
  const int colb = n0 + wni * WN + q15;
#pragma unroll
  for (int mh = 0; mh < 2; mh++)
#pragma unroll
    for (int mq = 0; mq < 4; mq++)
#pragma unroll
      for (int nq = 0; nq < NQ; nq++) {
        const f32x4 av = acc[mh][mq][nq];
        const int row = rowb + mh * 128 + mq * 16;
        const int col = colb + nq * 16;
        if (MODE == 4) {
          if (npart == 2) {          // k projection -> k_buf
            u16* Cout = (u16*)CoutV2;
            const int rk = row - NR;
            const int ck = col - 1280;
#pragma unroll
            for (int r = 0; r < 4; r++)
              Cout[(size_t)(rk + r) * HD + ck] = f2bf(av[r]);
          } else if (npart == 0) {   // q projection, row-major
            u16* Cout = (u16*)CoutV;
#pragma unroll
            for (int r = 0; r < 4; r++)
              Cout[(size_t)(row + r) * HD + col] = f2bf(av[r]);
          } else {                   // v projection, transposed store
            u16* Cout = (u16*)CoutV;
            const int vn = col - 640;
            const int bb = row >> 10;
            const int tl = row & 1023;
            u16x4 pk;
#pragma unroll
            for (int r = 0; r < 4; r++) pk[r] = f2bf(av[r]);
            *(u16x4*)&Cout[(size_t)(NR * HD) + ((size_t)(bb * HD + vn)) * TSEQ + tl] = pk;
          }
        } else {
          if (col < CC) {
            float* Cout = (float*)CoutV;
            const float bvv = bias[col];
#pragma unroll
            for (int r = 0; r < 4; r++)
              Cout[(size_t)(row + r) * CC + col] = av[r] + bvv;
          }
        }
      }
}

// ---------------- flash attention (DP=80, Q direct to regs) -------------
// q,k: [B,T,640] bf16 ; vt: [B,640,T] bf16 ; out attn: [16384][640] bf16 padded.
// QK^T: 2 full K32 chunks + one half-zeroed K32 tail (k 64..79 real, 80..95
// zeroed in both operands -> contributes 0). PV: 5 d-tiles (80 cols).
__global__ __launch_bounds__(256, 3) void attn_kernel(
    const u16* __restrict__ qb, const u16* __restrict__ kb,
    const u16* __restrict__ vt, u16* __restrict__ attn) {
  __shared__ u16 smem[11264 + 64 * 88 + 80 * 72];
  u16* Pt = smem;                       // per-wave [32 q][pitch 88]
  u16* Ks = smem + 11264;               // [64 s][88 pitch] (80 cols used)
  u16* Vs = smem + 11264 + 64 * 88;     // [80 d][72 pitch] (64 s cols used)

  const int tid  = threadIdx.x;
  const int lane = tid & 63;
  const int wave = tid >> 6;
  const int q15  = lane & 15;
  const int quad = lane >> 4;
  const int bid  = blockIdx.x;
  const int loc  = bid >> 3;
  const int pair = (bid & 7) * 16 + (loc >> 3);
  const int b  = pair >> 3;
  const int h  = pair & 7;
  const int t0 = (loc & 7) * 128;
  const int wq0 = wave * 32;
  const bool w3 = (tid < 128);          // waves 0,1 handle the 3rd chunk

  // staging geometry: K = 64 rows x 10 chunks; V = 80 rows x 8 chunks (640 each)
  int krow[3], kc[3], vrow[3], vc[3];
#pragma unroll
  for (int p = 0; p < 3; p++) {
    int qk = tid + 256 * p;
    krow[p] = qk / 10; kc[p] = (qk % 10) * 8;
    vrow[p] = qk >> 3; vc[p] = (qk & 7) * 8;
  }
  const u16* kbase = &kb[(size_t)(b * TSEQ) * HD + h * DP];
  const u16* vbase = &vt[(size_t)(b * HD + h * DP) * TSEQ];

  // Q fragments direct from global (B-operand of S^T); tail quads>=2 zeroed
  bf16x8 aq[2][2], aqt[2];
  {
    const u16x8 z = {0, 0, 0, 0, 0, 0, 0, 0};
#pragma unroll
    for (int n = 0; n < 2; n++) {
      const size_t qrow = (size_t)(b * TSEQ + t0 + wq0 + n * 16 + q15) * HD + h * DP;
#pragma unroll
      for (int kcx = 0; kcx < 2; kcx++)
        aq[n][kcx] = as_bf(*(const u16x8*)&qb[qrow + kcx * 32 + quad * 8]);
      u16x8 tload = z;
      if (quad < 2) tload = *(const u16x8*)&qb[qrow + 64 + quad * 8];
      aqt[n] = as_bf(tload);
    }
  }

  // zero pad cols 584..639 of this block's output rows
  if (tid < 128) {
    const u16x8 z = {0, 0, 0, 0, 0, 0, 0, 0};
    size_t base = (size_t)(b * TSEQ + t0 + tid) * KPW + CC;
#pragma unroll
    for (int c = 0; c < (KPW - CC) / 8; c++) *(u16x8*)&attn[base + c * 8] = z;
  }

  float lsum[2] = {0.f, 0.f};
  f32x4 oacc[2][5];
#pragma unroll
  for (int m = 0; m < 2; m++)
#pragma unroll
    for (int jd = 0; jd < 5; jd++) oacc[m][jd] = (f32x4){0.f, 0.f, 0.f, 0.f};

  u16* Ptw = &Pt[wave * 32 * PPITCH];

  u16x8 kreg[3], vreg[3];
#pragma unroll
  for (int p = 0; p < 2; p++) {
    kreg[p] = *(const u16x8*)&kbase[(size_t)krow[p] * HD + kc[p]];
    vreg[p] = *(const u16x8*)&vbase[(size_t)vrow[p] * TSEQ + vc[p]];
  }
  if (w3) {
    kreg[2] = *(const u16x8*)&kbase[(size_t)krow[2] * HD + kc[2]];
    vreg[2] = *(const u16x8*)&vbase[(size_t)vrow[2] * TSEQ + vc[2]];
  }

  for (int si = 0; si < 16; ++si) {
#pragma unroll
    for (int p = 0; p < 2; p++) {
      *(u16x8*)&Ks[krow[p] * 88 + kc[p]] = kreg[p];
      *(u16x8*)&Vs[vrow[p] * 72 + vc[p]] = vreg[p];
    }
    if (w3) {
      *(u16x8*)&Ks[krow[2] * 88 + kc[2]] = kreg[2];
      *(u16x8*)&Vs[vrow[2] * 72 + vc[2]] = vreg[2];
    }
    __syncthreads();

    if (si < 15) {
      const int s1 = (si + 1) * 64;
#pragma unroll
      for (int p = 0; p < 2; p++) {
        kreg[p] = *(const u16x8*)&kbase[(size_t)(s1 + krow[p]) * HD + kc[p]];
        vreg[p] = *(const u16x8*)&vbase[(size_t)vrow[p] * TSEQ + s1 + vc[p]];
      }
      if (w3) {
        kreg[2] = *(const u16x8*)&kbase[(size_t)(s1 + krow[2]) * HD + kc[2]];
        vreg[2] = *(const u16x8*)&vbase[(size_t)vrow[2] * TSEQ + s1 + vc[2]];
      }
    }

    // S^T = K Q^T : rows = s (4 tiles), cols = q (2 tiles)
    f32x4 st[4][2];
#pragma unroll
    for (int mt = 0; mt < 4; mt++)
#pragma unroll
      for (int n = 0; n < 2; n++) st[mt][n] = (f32x4){0.f, 0.f, 0.f, 0.f};
#pragma unroll
    for (int kcx = 0; kcx < 2; kcx++) {
      bf16x8 ak[4];
#pragma unroll
      for (int mt = 0; mt < 4; mt++)
        ak[mt] = as_bf(*(const u16x8*)&Ks[(mt * 16 + q15) * 88 + kcx * 32 + quad * 8]);
#pragma unroll
      for (int mt = 0; mt < 4; mt++)
#pragma unroll
        for (int n = 0; n < 2; n++)
          st[mt][n] = __builtin_amdgcn_mfma_f32_16x16x32_bf16(ak[mt], aq[n][kcx], st[mt][n], 0, 0, 0);
    }
    {  // tail: k 64..79 (quads >=2 zeroed on both operands)
      const u16x8 z = {0, 0, 0, 0, 0, 0, 0, 0};
#pragma unroll
      for (int mt = 0; mt < 4; mt++) {
        u16x8 tl = z;
        if (quad < 2) tl = *(const u16x8*)&Ks[(mt * 16 + q15) * 88 + 64 + quad * 8];
        bf16x8 akt = as_bf(tl);
#pragma unroll
        for (int n = 0; n < 2; n++)
          st[mt][n] = __builtin_amdgcn_mfma_f32_16x16x32_bf16(akt, aqt[n], st[mt][n], 0, 0, 0);
      }
    }

    // p = exp2(s*CEXP); per-lane partial row sums; vectorized Pt store (wave-private)
#pragma unroll
    for (int mt = 0; mt < 4; mt++)
#pragma unroll
      for (int n = 0; n < 2; n++) {
        f32x4 pv;
#pragma unroll
        for (int r = 0; r < 4; r++) pv[r] = __builtin_amdgcn_exp2f(st[mt][n][r] * CEXP);
        lsum[n] += (pv[0] + pv[1]) + (pv[2] + pv[3]);
        u16x4 pk;
#pragma unroll
        for (int r = 0; r < 4; r++) pk[r] = f2bf(pv[r]);
        *(u16x4*)&Ptw[(n * 16 + q15) * PPITCH + mt * 16 + quad * 4] = pk;
      }

    // O += P V  (A = P from Pt, b128 reads; B = V^T rows)
#pragma unroll
    for (int kcx = 0; kcx < 2; kcx++) {
      bf16x8 ap[2];
#pragma unroll
      for (int m = 0; m < 2; m++)
        ap[m] = as_bf(*(const u16x8*)&Ptw[(m * 16 + q15) * PPITCH + kcx * 32 + quad * 8]);
#pragma unroll
      for (int jd = 0; jd < 5; jd++) {
        bf16x8 bv = as_bf(*(const u16x8*)&Vs[(jd * 16 + q15) * 72 + kcx * 32 + quad * 8]);
#pragma unroll
        for (int m = 0; m < 2; m++)
          oacc[m][jd] = __builtin_amdgcn_mfma_f32_16x16x32_bf16(ap[m], bv, oacc[m][jd], 0, 0, 0);
      }
    }
    __syncthreads();
  }

  float lr[2];
#pragma unroll
  for (int n = 0; n < 2; n++) {
    float s = lsum[n];
    s += __shfl_xor(s, 16);
    s += __shfl_xor(s, 32);
    lr[n] = s;
  }

#pragma unroll
  for (int m = 0; m < 2; m++) {
#pragma unroll
    for (int r = 0; r < 4; r++) {
      const float inv = 1.f / __shfl(lr[m], quad * 4 + r);
      const int trow = t0 + wq0 + m * 16 + quad * 4 + r;
#pragma unroll
      for (int jd = 0; jd < 5; jd++) {
        const int d = jd * 16 + q15;
        if (d < DHD)
          attn[(size_t)(b * TSEQ + trow) * KPW + h * DHD + d] = f2bf(oacc[m][jd][r] * inv);
      }
    }
  }
}

// ---------------- launch ----------------

extern "C" void kernel_launch(void* const* d_in, const int* in_sizes, int n_in,
                              void* d_out, int out_size, void* d_ws, size_t ws_size,
                              hipStream_t stream) {
  const float* x   = (const float*)d_in[0];
  const float* mem = (const float*)d_in[1];
  const float* Wq  = (const float*)d_in[2];
  const float* Wk  = (const float*)d_in[3];
  const float* Wv  = (const float*)d_in[4];
  const float* Wp  = (const float*)d_in[5];
  const float* bp  = (const float*)d_in[6];
  float* out = (float*)d_out;

  char* ws = (char*)d_ws;
  const size_t SZ_XMB = (size_t)2 * NR * KPW * 2;  // 41,943,040
  const size_t SZ_WT  = (size_t)3 * HD * KPW * 2;  //  2,457,600 (q|v|k rows)
  const size_t SZ_WPT = (size_t)NP3 * KPW * 2;     //    983,040
  const size_t SZ_QB  = (size_t)NR * HD * 2;       // 20,971,520

  u16* xmb    = (u16*)(ws);            // [32768][640]; dead after projections
  u16* attn_o = (u16*)(ws);            // alias: [16384][640] padded
  u16* wt     = (u16*)(ws + SZ_XMB);
  u16* wp_t   = (u16*)(ws + SZ_XMB + SZ_WT);
  u16* q_buf  = (u16*)(ws + SZ_XMB + SZ_WT + SZ_WPT);       // q then vt contiguous
  u16* vt_buf = q_buf + (size_t)NR * HD;
  u16* k_buf  = (u16*)(ws + SZ_XMB + SZ_WT + SZ_WPT + 2 * SZ_QB);
  // total ws use: 41.9 + 2.5 + 1.0 + 62.9 MB ~= 108.3 MB

  (void)in_sizes; (void)n_in; (void)out_size; (void)ws_size;

  static bool s_attr = false;
  if (!s_attr) {
    (void)hipFuncSetAttribute((const void*)gemm8_kernel<4>,
                              hipFuncAttributeMaxDynamicSharedMemorySize, 114688);
    (void)hipFuncSetAttribute((const void*)gemm8_kernel<2>,
                              hipFuncAttributeMaxDynamicSharedMemorySize, 114688);
    s_attr = true;
  }

  // fused packs
  pack_all_kernel<<<PKA + PKB2 + PKC2, 256, 0, stream>>>(x, mem, Wq, Wk, Wv, Wp,
                                                         xmb, wt, wp_t);

  // all three projections in ONE launch (DP=80: 960 blocks, BN=128)
  gemm8_kernel<4><<<960, 512, 98304, stream>>>(xmb, wt, q_buf, k_buf, nullptr);

  // attention (writes attn_o with zeroed pad, aliasing dead xmb)
  attn_kernel<<<BB * HH * (TSEQ / 128), 256, 0, stream>>>(q_buf, k_buf, vt_buf, attn_o);

  // output projection + bias -> f32 out; 256 blocks = exactly 1 CU round
  gemm8_kernel<2><<<256, 512, 114688, stream>>>(attn_o, wp_t, out, nullptr, bp);
}

// Round 7
// 285.666 us; speedup vs baseline: 1.0568x; 1.0043x over previous
//
#include <hip/hip_runtime.h>
#include <hip/hip_bf16.h>

typedef unsigned short u16;
typedef __attribute__((ext_vector_type(4))) unsigned short u16x4;
typedef __attribute__((ext_vector_type(8))) unsigned short u16x8;
typedef __attribute__((ext_vector_type(8))) __bf16 bf16x8;
typedef __attribute__((ext_vector_type(4))) float f32x4;

#define BB 16
#define TSEQ 1024
#define CC 584          /* embed dim */
#define HH 8
#define DHD 73
#define NR (BB*TSEQ)    /* 16384 rows */
#define KPW 640         /* padded K: 10 x 64 K-tiles */
#define DP 80           /* padded head dim (73 -> 80 = 5x16) */
#define HD (HH*DP)      /* 640 */
#define NP3 768         /* padded N for final proj (4 x 192 tiles) */
#define PPITCH 88
/* exp(s*584^-0.5) == exp2(s * CEXP); scores bounded -> no max subtraction */
#define CEXP 0.0596985934f

__device__ __forceinline__ u16 f2bf(float f) {
  __bf16 h = (__bf16)f;                 // native v_cvt, RNE
  return __builtin_bit_cast(u16, h);
}
__device__ __forceinline__ bf16x8 as_bf(u16x8 v) { return __builtin_bit_cast(bf16x8, v); }

/* async global->LDS, 16B/lane, LDS dst = wave-uniform base + lane*16 */
#define GLL16(g, l) __builtin_amdgcn_global_load_lds( \
    (const __attribute__((address_space(1))) void*)(g), \
    (__attribute__((address_space(3))) void*)(l), 16, 0, 0)

#define BARRIER() asm volatile("s_barrier" ::: "memory")
#define VMW7()    asm volatile("s_waitcnt vmcnt(7)" ::: "memory")
#define VMW6()    asm volatile("s_waitcnt vmcnt(6)" ::: "memory")
#define VMW2()    asm volatile("s_waitcnt vmcnt(2)" ::: "memory")
#define VMW0()    asm volatile("s_waitcnt vmcnt(0)" ::: "memory")

// ---------------- fused pack kernel ----------------
// phase A (1280 blocks x 2048 chunks): x|mem f32 -> xmb [32768][640] bf16 zero-pad
// phase B (600 blocks x 2048): Wq/Wv/Wk -> wt [q 640 | v 640 | k 640 rows][640]
// phase C (240 blocks x 2048): Wp -> wpt [768][640] bf16 (transposed)
#define PKA2 1280
#define PKB2 600
#define PKC2 240
__global__ void pack_all_kernel(const float* __restrict__ x, const float* __restrict__ mem,
                                const float* __restrict__ Wq, const float* __restrict__ Wk,
                                const float* __restrict__ Wv, const float* __restrict__ Wp,
                                u16* __restrict__ xmb, u16* __restrict__ wt,
                                u16* __restrict__ wpt) {
  const int bidx = blockIdx.x;
  const int tid = threadIdx.x;
  if (bidx < PKA2) {
    const int base = bidx * 2048 + tid;
#pragma unroll
    for (int e = 0; e < 8; e++) {
      int idx = base + e * 256;
      int row = idx / (KPW / 8);
      int c8  = (idx % (KPW / 8)) * 8;
      u16x8 o = {0, 0, 0, 0, 0, 0, 0, 0};
      if (c8 < CC) {
        const float* src = (row < NR) ? &x[(size_t)row * CC + c8]
                                      : &mem[(size_t)(row - NR) * CC + c8];
        f32x4 a = *(const f32x4*)src;
        f32x4 b = *(const f32x4*)(src + 4);
#pragma unroll
        for (int t = 0; t < 4; t++) { o[t] = f2bf(a[t]); o[4 + t] = f2bf(b[t]); }
      }
      *(u16x8*)&xmb[(size_t)row * KPW + c8] = o;
    }
  } else if (bidx < PKA2 + PKB2) {
    const int base = (bidx - PKA2) * 2048 + tid;
#pragma unroll
    for (int e = 0; e < 8; e++) {
      int idx = base + e * 256;
      int w   = idx / (HD * KPW);
      int rem = idx % (HD * KPW);
      int n = rem / KPW;
      int k = rem % KPW;
      int h = n / DP, d = n % DP;
      u16 val = 0;
      if (d < DHD && k < CC) {
        const float* W = (w == 0) ? Wq : ((w == 1) ? Wv : Wk);  // order: q, v, k
        val = f2bf(W[((size_t)h * CC + k) * DHD + d]);
      }
      wt[idx] = val;
    }
  } else {
    const int base = (bidx - PKA2 - PKB2) * 2048 + tid;
#pragma unroll
    for (int e = 0; e < 8; e++) {
      int idx = base + e * 256;
      int n = idx / KPW;
      int c = idx % KPW;
      u16 val = 0;
      if (n < CC && c < CC) val = f2bf(Wp[(size_t)c * CC + n]);
      wpt[idx] = val;
    }
  }
}

// ---------------- 256xBN GEMM, 2-phase/K-tile (r5/r6-proven schedule) ----------------
// MODE4: BN=128 (NB=2). wt 1920 rows: grid 960. MODE2: BN=192 (NB=3), grid 256.
// Schedule + vmcnt retire proof unchanged from r6 (verified passing).

__device__ __forceinline__ void rd_a4(bf16x8 (&a)[4][2], const u16* lds, int base,
                                      int sw0, int sw1) {
#pragma unroll
  for (int mq = 0; mq < 4; mq++) {
    const int r = base + mq * 1024;
    a[mq][0] = as_bf(*(const u16x8*)&lds[r + sw0]);
    a[mq][1] = as_bf(*(const u16x8*)&lds[r + sw1]);
  }
}
template <int NQ>
__device__ __forceinline__ void rd_bn(bf16x8 (&b)[NQ][2], const u16* lds, int base,
                                      int sw0, int sw1) {
#pragma unroll
  for (int nq = 0; nq < NQ; nq++) {
    const int r = base + nq * 1024;
    b[nq][0] = as_bf(*(const u16x8*)&lds[r + sw0]);
    b[nq][1] = as_bf(*(const u16x8*)&lds[r + sw1]);
  }
}
__device__ __forceinline__ void s_a1(const u16* gA, u16* ldst, int t, int lb) {
  GLL16(gA + (size_t)128 * KPW + (size_t)t * 64, ldst + lb + 8192);
  GLL16(gA + (size_t)192 * KPW + (size_t)t * 64, ldst + lb + 12288);
}
template <int NB>
__device__ __forceinline__ void s_a0b(const u16* gA, const u16* gB, u16* ldst,
                                      int t, int lb) {
  GLL16(gA + (size_t)t * 64, ldst + lb);
  GLL16(gA + (size_t)64 * KPW + (size_t)t * 64, ldst + lb + 4096);
#pragma unroll
  for (int u = 0; u < NB; u++)
    GLL16(gB + (size_t)(u * 64) * KPW + (size_t)t * 64, ldst + lb + 16384 + u * 4096);
}
template <int NQ>
__device__ __forceinline__ void mm4n(f32x4 (&acc)[4][NQ], const bf16x8 (&a)[4][2],
                                     const bf16x8 (&b)[NQ][2]) {
  __builtin_amdgcn_s_setprio(1);
#pragma unroll
  for (int mq = 0; mq < 4; mq++)
#pragma unroll
    for (int nq = 0; nq < NQ; nq++) {
      f32x4 c = acc[mq][nq];
      c = __builtin_amdgcn_mfma_f32_16x16x32_bf16(a[mq][0], b[nq][0], c, 0, 0, 0);
      c = __builtin_amdgcn_mfma_f32_16x16x32_bf16(a[mq][1], b[nq][1], c, 0, 0, 0);
      acc[mq][nq] = c;
    }
  __builtin_amdgcn_s_setprio(0);
}

template <int MODE>
__global__ __launch_bounds__(512, 2) void gemm8_kernel(
    const u16* __restrict__ A, const u16* __restrict__ Bt,
    void* __restrict__ CoutV, void* __restrict__ CoutV2,
    const float* __restrict__ bias) {
  constexpr int NB = (MODE == 4) ? 2 : 3;   // B 64-row units
  constexpr int NQ = NB;                    // n-frags per wave (32 or 48 cols)
  constexpr int WN = NQ * 16;
  constexpr int SB = 16384 + NB * 4096;     // LDS buf stride (u16)
  extern __shared__ u16 lds[];
  const int tid  = threadIdx.x;
  const int lane = tid & 63;
  const int q15  = lane & 15;
  const int quad = lane >> 4;
  const int wave = tid >> 6;
  const int wmi  = wave >> 2;     // 0..1
  const int wni  = wave & 3;      // 0..3

  // XCD-contiguous swizzle (grid % 8 == 0 for both modes)
  const int cpx = gridDim.x >> 3;
  const int bid = (blockIdx.x & 7) * cpx + (blockIdx.x >> 3);

  int m0, n0, npart;  // npart: 0=q 1=v 2=k (MODE4)
  if (MODE == 4) {
    if (bid < 640) {
      m0 = (bid / 10) * 256; int nt = bid % 10;
      if (nt < 5) { n0 = nt * 128; npart = 0; }
      else        { n0 = 640 + (nt - 5) * 128; npart = 1; }
    } else {
      int b2 = bid - 640;
      m0 = NR + (b2 / 5) * 256; n0 = 1280 + (b2 % 5) * 128; npart = 2;
    }
  } else {
    m0 = (bid >> 2) * 256; n0 = (bid & 3) * 192; npart = 0;
  }

  // staging geometry: thread t covers (row = t>>3, chunk = t&7) of a 64-row unit;
  // source chunk pre-swizzled so swizzled ds_read finds linear data (T2 rule 21).
  const int tr   = tid >> 3;
  const int scol = ((tid & 7) ^ (tr & 7)) * 8;
  const u16* gA = &A[(size_t)(m0 + tr) * KPW + scol];
  const u16* gB = &Bt[(size_t)(n0 + tr) * KPW + scol];
  u16* ldst = &lds[tid * 8];

  // fragment-read swizzled 16B-slot offsets (frag row & 7 == q15 & 7)
  const int rb  = q15 & 7;
  const int sw0 = (quad ^ rb) * 8;
  const int sw1 = ((quad + 4) ^ rb) * 8;
  const int arow = (wmi * 64 + q15) * 64;          // within A half (128 rows)
  const int brow = (wni * WN + q15) * 64;          // within B (BN rows)

  f32x4 acc[2][4][NQ];
#pragma unroll
  for (int i = 0; i < 2; i++)
#pragma unroll
    for (int j = 0; j < 4; j++)
#pragma unroll
      for (int k = 0; k < NQ; k++) acc[i][j][k] = (f32x4){0.f, 0.f, 0.f, 0.f};
  bf16x8 a[4][2], b[NQ][2];

  // prologue: (0).A0B, (0).A1, (1).A0B; vmcnt(4+NB) retires (0).A0B
  s_a0b<NB>(gA, gB, ldst, 0, 0);
  s_a1(gA, ldst, 0, 0);
  s_a0b<NB>(gA, gB, ldst, 1, SB);
  if constexpr (NB == 2) VMW6(); else VMW7();
  BARRIER();

#pragma unroll 1
  for (int t = 0; t < 10; ++t) {
    const int lb = (t & 1) * SB;
    const int lbo = lb ^ SB;
    // ph_a: compute (mh=0); B read once for both phases
    rd_a4(a, lds, lb + arow, sw0, sw1);
    rd_bn<NQ>(b, lds, lb + 16384 + brow, sw0, sw1);
    if (t < 9) s_a1(gA, ldst, t + 1, lbo);
    if (t == 9) { VMW0(); } else { if constexpr (NB == 2) VMW6(); else VMW7(); }
    BARRIER();
    mm4n<NQ>(acc[0], a, b);
    BARRIER();
    // ph_b: compute (mh=1)
    rd_a4(a, lds, lb + 8192 + arow, sw0, sw1);
    if (t < 8) { s_a0b<NB>(gA, gB, ldst, t + 2, lb);
                 if constexpr (NB == 2) VMW6(); else VMW7(); }
    else if (t == 8) { VMW2(); }
    BARRIER();
    mm4n<NQ>(acc[1], a, b);
    BARRIER();
  }

  // epilogue: row = m0 + mh*128 + wmi*64 + mq*16 + quad*4 + r
  //           col = n0 + wni*WN + nq*16 + q15
  const int rowb = m0 + wmi * 64 + quad * 4;
  const int colb = n0 + wni * WN + q15;
#pragma unroll
  for (int mh = 0; mh < 2; mh++)
#pragma unroll
    for (int mq = 0; mq < 4; mq++)
#pragma unroll
      for (int nq = 0; nq < NQ; nq++) {
        const f32x4 av = acc[mh][mq][nq];
        const int row = rowb + mh * 128 + mq * 16;
        const int col = colb + nq * 16;
        if (MODE == 4) {
          if (npart == 2) {          // k projection -> k_buf
            u16* Cout = (u16*)CoutV2;
            const int rk = row - NR;
            const int ck = col - 1280;
#pragma unroll
            for (int r = 0; r < 4; r++)
              Cout[(size_t)(rk + r) * HD + ck] = f2bf(av[r]);
          } else if (npart == 0) {   // q projection, row-major
            u16* Cout = (u16*)CoutV;
#pragma unroll
            for (int r = 0; r < 4; r++)
              Cout[(size_t)(row + r) * HD + col] = f2bf(av[r]);
          } else {                   // v projection, transposed store
            u16* Cout = (u16*)CoutV;
            const int vn = col - 640;
            const int bb = row >> 10;
            const int tl = row & 1023;
            u16x4 pk;
#pragma unroll
            for (int r = 0; r < 4; r++) pk[r] = f2bf(av[r]);
            *(u16x4*)&Cout[(size_t)(NR * HD) + ((size_t)(bb * HD + vn)) * TSEQ + tl] = pk;
          }
        } else {
          if (col < CC) {
            float* Cout = (float*)CoutV;
            const float bvv = bias[col];
#pragma unroll
            for (int r = 0; r < 4; r++)
              Cout[(size_t)(row + r) * CC + col] = av[r] + bvv;
          }
        }
      }
}

// ---------------- flash attention: 8-wave blocks, QBLK=256 -------------
// q,k: [B,T,640] bf16 ; vt: [B,640,T] bf16 ; out attn: [16384][640] bf16 padded.
// Grid 512 = ALL blocks co-resident (2/CU); K/V staged once per 256 q rows
// (staging ops + global K/V reads halved vs QBLK=128). Per-wave math identical
// to r6 (QK 2 full K32 chunks + half-zeroed tail; PV 5 d-tiles).
__global__ __launch_bounds__(512, 2) void attn_kernel(
    const u16* __restrict__ qb, const u16* __restrict__ kb,
    const u16* __restrict__ vt, u16* __restrict__ attn) {
  extern __shared__ u16 alds[];
  u16* Pt = alds;                       // 8 waves x [32 q][pitch 88]
  u16* Ks = alds + 8 * 32 * PPITCH;     // [64 s][88 pitch] (80 cols used)
  u16* Vs = Ks + 64 * 88;               // [80 d][72 pitch] (64 s cols used)

  const int tid  = threadIdx.x;
  const int lane = tid & 63;
  const int wave = tid >> 6;            // 0..7
  const int q15  = lane & 15;
  const int quad = lane >> 4;
  const int bid  = blockIdx.x;
  const int loc  = bid >> 3;            // 0..63
  const int pair = (bid & 7) * 16 + (loc >> 2);  // all 4 t-tiles of (b,h) on one XCD
  const int b  = pair >> 3;
  const int h  = pair & 7;
  const int t0 = (loc & 3) * 256;
  const int wq0 = wave * 32;
  const bool p1 = (tid < 128);          // second chunk ownership

  // chunk assignment: K tile 64 rows x 10 chunks (640); V tile 80 rows x 8 (640)
  const int k0r = tid / 10,          k0c = (tid % 10) * 8;
  const int k1r = (512 + tid) / 10,  k1c = ((512 + tid) % 10) * 8;  // p1 only
  const int v0r = tid >> 3,          v0c = (tid & 7) * 8;
  const int v1r = 64 + (tid >> 3),   v1c = v0c;                     // p1 only
  const u16* kbase = &kb[(size_t)(b * TSEQ) * HD + h * DP];
  const u16* vbase = &vt[(size_t)(b * HD + h * DP) * TSEQ];

  // Q fragments direct from global (B-operand of S^T); tail quads>=2 zeroed
  bf16x8 aq[2][2], aqt[2];
  {
    const u16x8 z = {0, 0, 0, 0, 0, 0, 0, 0};
#pragma unroll
    for (int n = 0; n < 2; n++) {
      const size_t qrow = (size_t)(b * TSEQ + t0 + wq0 + n * 16 + q15) * HD + h * DP;
#pragma unroll
      for (int kcx = 0; kcx < 2; kcx++)
        aq[n][kcx] = as_bf(*(const u16x8*)&qb[qrow + kcx * 32 + quad * 8]);
      u16x8 tload = z;
      if (quad < 2) tload = *(const u16x8*)&qb[qrow + 64 + quad * 8];
      aqt[n] = as_bf(tload);
    }
  }

  // zero pad cols 584..639 of this block's 256 output rows
  if (tid < 256) {
    const u16x8 z = {0, 0, 0, 0, 0, 0, 0, 0};
    size_t base = (size_t)(b * TSEQ + t0 + tid) * KPW + CC;
#pragma unroll
    for (int c = 0; c < (KPW - CC) / 8; c++) *(u16x8*)&attn[base + c * 8] = z;
  }

  float lsum[2] = {0.f, 0.f};
  f32x4 oacc[2][5];
#pragma unroll
  for (int m = 0; m < 2; m++)
#pragma unroll
    for (int jd = 0; jd < 5; jd++) oacc[m][jd] = (f32x4){0.f, 0.f, 0.f, 0.f};

  u16* Ptw = &Pt[wave * 32 * PPITCH];

  // prefetch tile 0 into registers
  u16x8 kreg0, kreg1, vreg0, vreg1;
  kreg0 = *(const u16x8*)&kbase[(size_t)k0r * HD + k0c];
  vreg0 = *(const u16x8*)&vbase[(size_t)v0r * TSEQ + v0c];
  if (p1) {
    kreg1 = *(const u16x8*)&kbase[(size_t)k1r * HD + k1c];
    vreg1 = *(const u16x8*)&vbase[(size_t)v1r * TSEQ + v1c];
  }

  for (int si = 0; si < 16; ++si) {
    *(u16x8*)&Ks[k0r * 88 + k0c] = kreg0;
    *(u16x8*)&Vs[v0r * 72 + v0c] = vreg0;
    if (p1) {
      *(u16x8*)&Ks[k1r * 88 + k1c] = kreg1;
      *(u16x8*)&Vs[v1r * 72 + v1c] = vreg1;
    }
    __syncthreads();

    if (si < 15) {
      const int s1 = (si + 1) * 64;
      kreg0 = *(const u16x8*)&kbase[(size_t)(s1 + k0r) * HD + k0c];
      vreg0 = *(const u16x8*)&vbase[(size_t)v0r * TSEQ + s1 + v0c];
      if (p1) {
        kreg1 = *(const u16x8*)&kbase[(size_t)(s1 + k1r) * HD + k1c];
        vreg1 = *(const u16x8*)&vbase[(size_t)v1r * TSEQ + s1 + v1c];
      }
    }

    // S^T = K Q^T : rows = s (4 tiles), cols = q (2 tiles)
    f32x4 st[4][2];
#pragma unroll
    for (int mt = 0; mt < 4; mt++)
#pragma unroll
      for (int n = 0; n < 2; n++) st[mt][n] = (f32x4){0.f, 0.f, 0.f, 0.f};
#pragma unroll
    for (int kcx = 0; kcx < 2; kcx++) {
      bf16x8 ak[4];
#pragma unroll
      for (int mt = 0; mt < 4; mt++)
        ak[mt] = as_bf(*(const u16x8*)&Ks[(mt * 16 + q15) * 88 + kcx * 32 + quad * 8]);
#pragma unroll
      for (int mt = 0; mt < 4; mt++)
#pragma unroll
        for (int n = 0; n < 2; n++)
          st[mt][n] = __builtin_amdgcn_mfma_f32_16x16x32_bf16(ak[mt], aq[n][kcx], st[mt][n], 0, 0, 0);
    }
    {  // tail: k 64..79 (quads >=2 zeroed on both operands)
      const u16x8 z = {0, 0, 0, 0, 0, 0, 0, 0};
#pragma unroll
      for (int mt = 0; mt < 4; mt++) {
        u16x8 tl = z;
        if (quad < 2) tl = *(const u16x8*)&Ks[(mt * 16 + q15) * 88 + 64 + quad * 8];
        bf16x8 akt = as_bf(tl);
#pragma unroll
        for (int n = 0; n < 2; n++)
          st[mt][n] = __builtin_amdgcn_mfma_f32_16x16x32_bf16(akt, aqt[n], st[mt][n], 0, 0, 0);
      }
    }

    // p = exp2(s*CEXP); per-lane partial row sums; vectorized Pt store (wave-private)
#pragma unroll
    for (int mt = 0; mt < 4; mt++)
#pragma unroll
      for (int n = 0; n < 2; n++) {
        f32x4 pv;
#pragma unroll
        for (int r = 0; r < 4; r++) pv[r] = __builtin_amdgcn_exp2f(st[mt][n][r] * CEXP);
        lsum[n] += (pv[0] + pv[1]) + (pv[2] + pv[3]);
        u16x4 pk;
#pragma unroll
        for (int r = 0; r < 4; r++) pk[r] = f2bf(pv[r]);
        *(u16x4*)&Ptw[(n * 16 + q15) * PPITCH + mt * 16 + quad * 4] = pk;
      }

    // O += P V  (A = P from Pt, b128 reads; B = V^T rows) — same-wave DS ordering
#pragma unroll
    for (int kcx = 0; kcx < 2; kcx++) {
      bf16x8 ap[2];
#pragma unroll
      for (int m = 0; m < 2; m++)
        ap[m] = as_bf(*(const u16x8*)&Ptw[(m * 16 + q15) * PPITCH + kcx * 32 + quad * 8]);
#pragma unroll
      for (int jd = 0; jd < 5; jd++) {
        bf16x8 bv = as_bf(*(const u16x8*)&Vs[(jd * 16 + q15) * 72 + kcx * 32 + quad * 8]);
#pragma unroll
        for (int m = 0; m < 2; m++)
          oacc[m][jd] = __builtin_amdgcn_mfma_f32_16x16x32_bf16(ap[m], bv, oacc[m][jd], 0, 0, 0);
      }
    }
    __syncthreads();
  }

  float lr[2];
#pragma unroll
  for (int n = 0; n < 2; n++) {
    float s = lsum[n];
    s += __shfl_xor(s, 16);
    s += __shfl_xor(s, 32);
    lr[n] = s;
  }

#pragma unroll
  for (int m = 0; m < 2; m++) {
#pragma unroll
    for (int r = 0; r < 4; r++) {
      const float inv = 1.f / __shfl(lr[m], quad * 4 + r);
      const int trow = t0 + wq0 + m * 16 + quad * 4 + r;
#pragma unroll
      for (int jd = 0; jd < 5; jd++) {
        const int d = jd * 16 + q15;
        if (d < DHD)
          attn[(size_t)(b * TSEQ + trow) * KPW + h * DHD + d] = f2bf(oacc[m][jd][r] * inv);
      }
    }
  }
}

// ---------------- launch ----------------

extern "C" void kernel_launch(void* const* d_in, const int* in_sizes, int n_in,
                              void* d_out, int out_size, void* d_ws, size_t ws_size,
                              hipStream_t stream) {
  const float* x   = (const float*)d_in[0];
  const float* mem = (const float*)d_in[1];
  const float* Wq  = (const float*)d_in[2];
  const float* Wk  = (const float*)d_in[3];
  const float* Wv  = (const float*)d_in[4];
  const float* Wp  = (const float*)d_in[5];
  const float* bp  = (const float*)d_in[6];
  float* out = (float*)d_out;

  char* ws = (char*)d_ws;
  const size_t SZ_XMB = (size_t)2 * NR * KPW * 2;  // 41,943,040
  const size_t SZ_WT  = (size_t)3 * HD * KPW * 2;  //  2,457,600 (q|v|k rows)
  const size_t SZ_WPT = (size_t)NP3 * KPW * 2;     //    983,040
  const size_t SZ_QB  = (size_t)NR * HD * 2;       // 20,971,520

  u16* xmb    = (u16*)(ws);            // [32768][640]; dead after projections
  u16* attn_o = (u16*)(ws);            // alias: [16384][640] padded
  u16* wt     = (u16*)(ws + SZ_XMB);
  u16* wp_t   = (u16*)(ws + SZ_XMB + SZ_WT);
  u16* q_buf  = (u16*)(ws + SZ_XMB + SZ_WT + SZ_WPT);       // q then vt contiguous
  u16* vt_buf = q_buf + (size_t)NR * HD;
  u16* k_buf  = (u16*)(ws + SZ_XMB + SZ_WT + SZ_WPT + 2 * SZ_QB);
  // total ws use: 41.9 + 2.5 + 1.0 + 62.9 MB ~= 108.3 MB

  (void)in_sizes; (void)n_in; (void)out_size; (void)ws_size;

  static bool s_attr = false;
  if (!s_attr) {
    (void)hipFuncSetAttribute((const void*)gemm8_kernel<4>,
                              hipFuncAttributeMaxDynamicSharedMemorySize, 114688);
    (void)hipFuncSetAttribute((const void*)gemm8_kernel<2>,
                              hipFuncAttributeMaxDynamicSharedMemorySize, 114688);
    (void)hipFuncSetAttribute((const void*)attn_kernel,
                              hipFuncAttributeMaxDynamicSharedMemorySize, 67840);
    s_attr = true;
  }

  // fused packs (fattened blocks: 2120 total)
  pack_all_kernel<<<PKA2 + PKB2 + PKC2, 256, 0, stream>>>(x, mem, Wq, Wk, Wv, Wp,
                                                          xmb, wt, wp_t);

  // all three projections in ONE launch (DP=80: 960 blocks, BN=128)
  gemm8_kernel<4><<<960, 512, 98304, stream>>>(xmb, wt, q_buf, k_buf, nullptr);

  // attention: 512 blocks x 512 threads, all co-resident
  attn_kernel<<<BB * HH * (TSEQ / 256), 512, 67840, stream>>>(q_buf, k_buf, vt_buf, attn_o);

  // output projection + bias -> f32 out; 256 blocks = exactly 1 CU round
  gemm8_kernel<2><<<256, 512, 114688, stream>>>(attn_o, wp_t, out, nullptr, bp);
}

// Round 8
// 275.983 us; speedup vs baseline: 1.0939x; 1.0351x over previous
//
#include <hip/hip_runtime.h>
#include <hip/hip_bf16.h>

typedef unsigned short u16;
typedef __attribute__((ext_vector_type(4))) unsigned short u16x4;
typedef __attribute__((ext_vector_type(8))) unsigned short u16x8;
typedef __attribute__((ext_vector_type(8))) __bf16 bf16x8;
typedef __attribute__((ext_vector_type(4))) float f32x4;

#define BB 16
#define TSEQ 1024
#define CC 584          /* embed dim */
#define HH 8
#define DHD 73
#define NR (BB*TSEQ)    /* 16384 rows */
#define KPW 640         /* padded K: 10 x 64 K-tiles */
#define DP 80           /* padded head dim (73 -> 80 = 5x16) */
#define HD (HH*DP)      /* 640 */
#define NP3 768         /* padded N for final proj */
#define PPITCH 88
/* exp(s*584^-0.5) == exp2(s * CEXP); scores bounded -> no max subtraction */
#define CEXP 0.0596985934f

__device__ __forceinline__ u16 f2bf(float f) {
  __bf16 h = (__bf16)f;                 // native v_cvt, RNE
  return __builtin_bit_cast(u16, h);
}
__device__ __forceinline__ bf16x8 as_bf(u16x8 v) { return __builtin_bit_cast(bf16x8, v); }

/* async global->LDS, 16B/lane, LDS dst = wave-uniform base + lane*16 */
#define GLL16(g, l) __builtin_amdgcn_global_load_lds( \
    (const __attribute__((address_space(1))) void*)(g), \
    (__attribute__((address_space(3))) void*)(l), 16, 0, 0)

#define BARRIER() asm volatile("s_barrier" ::: "memory")
#define VMW8()    asm volatile("s_waitcnt vmcnt(8)" ::: "memory")
#define VMW0()    asm volatile("s_waitcnt vmcnt(0)" ::: "memory")

// ---------------- fused pack kernel (r7 config, kept) ----------------
#define PKA2 1280
#define PKB2 600
#define PKC2 240
__global__ void pack_all_kernel(const float* __restrict__ x, const float* __restrict__ mem,
                                const float* __restrict__ Wq, const float* __restrict__ Wk,
                                const float* __restrict__ Wv, const float* __restrict__ Wp,
                                u16* __restrict__ xmb, u16* __restrict__ wt,
                                u16* __restrict__ wpt) {
  const int bidx = blockIdx.x;
  const int tid = threadIdx.x;
  if (bidx < PKA2) {
    const int base = bidx * 2048 + tid;
#pragma unroll
    for (int e = 0; e < 8; e++) {
      int idx = base + e * 256;
      int row = idx / (KPW / 8);
      int c8  = (idx % (KPW / 8)) * 8;
      u16x8 o = {0, 0, 0, 0, 0, 0, 0, 0};
      if (c8 < CC) {
        const float* src = (row < NR) ? &x[(size_t)row * CC + c8]
                                      : &mem[(size_t)(row - NR) * CC + c8];
        f32x4 a = *(const f32x4*)src;
        f32x4 b = *(const f32x4*)(src + 4);
#pragma unroll
        for (int t = 0; t < 4; t++) { o[t] = f2bf(a[t]); o[4 + t] = f2bf(b[t]); }
      }
      *(u16x8*)&xmb[(size_t)row * KPW + c8] = o;
    }
  } else if (bidx < PKA2 + PKB2) {
    const int base = (bidx - PKA2) * 2048 + tid;
#pragma unroll
    for (int e = 0; e < 8; e++) {
      int idx = base + e * 256;
      int w   = idx / (HD * KPW);
      int rem = idx % (HD * KPW);
      int n = rem / KPW;
      int k = rem % KPW;
      int h = n / DP, d = n % DP;
      u16 val = 0;
      if (d < DHD && k < CC) {
        const float* W = (w == 0) ? Wq : ((w == 1) ? Wv : Wk);  // order: q, v, k
        val = f2bf(W[((size_t)h * CC + k) * DHD + d]);
      }
      wt[idx] = val;
    }
  } else {
    const int base = (bidx - PKA2 - PKB2) * 2048 + tid;
#pragma unroll
    for (int e = 0; e < 8; e++) {
      int idx = base + e * 256;
      int n = idx / KPW;
      int c = idx % KPW;
      u16 val = 0;
      if (n < CC && c < CC) val = f2bf(Wp[(size_t)c * CC + n]);
      wpt[idx] = val;
    }
  }
}

// ---------------- 128x128 GEMM, BK=64 dbuf, 2 blocks/CU ----------------
// 256 threads = 4 waves (2M x 2N); wave owns 64x64 of C. LDS = 2 bufs x
// (A[128][64] + B[128][64]) bf16 = 64 KB exactly -> 2 blocks/CU: block
// prologue/epilogue/drain of one block overlaps steady-state of the other
// (the lever untested so far; all 1-block/CU structures tied at ~607 TF).
// Per K-tile t (buf=t&1): {16 ds_read_b128; 32 MFMA (compiler counted lgkm)};
// BARRIER; stage(t+2 -> buf t&1)[8 GLL16]; VMW8 retires tile t+1; BARRIER.
// Retire/clobber proof: after stage(t+2), outstanding = 8(t+1)+8(t+2);
// VMW8 -> t+1 landed (read next iter). stage(t+2) writes buf(t&1) only after
// the post-compute barrier (all waves done reading t). Tails: t=8 VMW0;
// t=9 no trailing barrier. T2 swizzle identical to r5-r7 (0 conflicts).

__device__ __forceinline__ void rd4(bf16x8 (&v)[4][2], const u16* lds, int base,
                                    int sw0, int sw1) {
#pragma unroll
  for (int q = 0; q < 4; q++) {
    const int r = base + q * 1024;
    v[q][0] = as_bf(*(const u16x8*)&lds[r + sw0]);
    v[q][1] = as_bf(*(const u16x8*)&lds[r + sw1]);
  }
}
__device__ __forceinline__ void stg128(const u16* gA, const u16* gB, u16* ldst, int t) {
  const int lb = (t & 1) * 8192;
  const size_t ko = (size_t)t * 64;
#pragma unroll
  for (int u = 0; u < 4; u++)
    GLL16(gA + (size_t)(u * 32) * KPW + ko, ldst + lb + u * 2048);
#pragma unroll
  for (int u = 0; u < 4; u++)
    GLL16(gB + (size_t)(u * 32) * KPW + ko, ldst + 16384 + lb + u * 2048);
}

// MODE 4: A = xmb [32768][640]; bid<1280: x rows (nt<5 q; else v); bid>=1280:
//   mem rows, k cols 1280..1919. MODE 2: final proj + bias -> f32, col<584.
template <int MODE>
__global__ __launch_bounds__(256, 2) void gemm8_kernel(
    const u16* __restrict__ A, const u16* __restrict__ Bt,
    void* __restrict__ CoutV, void* __restrict__ CoutV2,
    const float* __restrict__ bias) {
  extern __shared__ u16 lds[];
  const int tid  = threadIdx.x;
  const int lane = tid & 63;
  const int q15  = lane & 15;
  const int quad = lane >> 4;
  const int wave = tid >> 6;      // 0..3
  const int wmi  = wave >> 1;     // 0..1
  const int wni  = wave & 1;      // 0..1

  // XCD-contiguous swizzle (grid % 8 == 0 for both modes)
  const int cpx = gridDim.x >> 3;
  const int bid = (blockIdx.x & 7) * cpx + (blockIdx.x >> 3);

  int m0, n0, npart;  // npart: 0=q 1=v 2=k (MODE4)
  if (MODE == 4) {
    if (bid < 1280) {
      m0 = (bid / 10) * 128; int nt = bid % 10;
      if (nt < 5) { n0 = nt * 128; npart = 0; }
      else        { n0 = 640 + (nt - 5) * 128; npart = 1; }
    } else {
      int b2 = bid - 1280;
      m0 = NR + (b2 / 5) * 128; n0 = 1280 + (b2 % 5) * 128; npart = 2;
    }
  } else {
    m0 = (bid / 6) * 128; n0 = (bid % 6) * 128; npart = 0;
  }

  // staging: thread t covers (row = t>>3 in a 32-row unit, chunk = t&7);
  // source chunk pre-swizzled so swizzled ds_read finds linear data (rule 21).
  const int tr   = tid >> 3;
  const int scol = ((tid & 7) ^ (tr & 7)) * 8;
  const u16* gA = &A[(size_t)(m0 + tr) * KPW + scol];
  const u16* gB = &Bt[(size_t)(n0 + tr) * KPW + scol];
  u16* ldst = &lds[tid * 8];

  // fragment-read swizzled 16B-slot offsets (frag row & 7 == q15 & 7)
  const int rb  = q15 & 7;
  const int sw0 = (quad ^ rb) * 8;
  const int sw1 = ((quad + 4) ^ rb) * 8;
  const int arow = (wmi * 64 + q15) * 64;
  const int brow = (wni * 64 + q15) * 64;

  f32x4 acc[4][4];
#pragma unroll
  for (int i = 0; i < 4; i++)
#pragma unroll
    for (int j = 0; j < 4; j++) acc[i][j] = (f32x4){0.f, 0.f, 0.f, 0.f};

  // prologue: tiles 0 and 1 staged; VMW8 -> tile 0 landed
  stg128(gA, gB, ldst, 0);
  stg128(gA, gB, ldst, 1);
  VMW8(); BARRIER();

#pragma unroll 1
  for (int t = 0; t < 10; ++t) {
    const int lb = (t & 1) * 8192;
    bf16x8 a[4][2], b[4][2];
    rd4(a, lds, lb + arow, sw0, sw1);
    rd4(b, lds, 16384 + lb + brow, sw0, sw1);
    __builtin_amdgcn_s_setprio(1);
#pragma unroll
    for (int mq = 0; mq < 4; mq++)
#pragma unroll
      for (int nq = 0; nq < 4; nq++) {
        f32x4 c = acc[mq][nq];
        c = __builtin_amdgcn_mfma_f32_16x16x32_bf16(a[mq][0], b[nq][0], c, 0, 0, 0);
        c = __builtin_amdgcn_mfma_f32_16x16x32_bf16(a[mq][1], b[nq][1], c, 0, 0, 0);
        acc[mq][nq] = c;
      }
    __builtin_amdgcn_s_setprio(0);
    if (t == 9) break;
    BARRIER();                       // all waves done reading buf(t)
    if (t < 8) { stg128(gA, gB, ldst, t + 2); VMW8(); }
    else       { VMW0(); }
    BARRIER();                       // tile t+1 visible
  }

  // epilogue: row = m0 + wmi*64 + mq*16 + quad*4 + r ; col = n0 + wni*64 + nq*16 + q15
  const int rowb = m0 + wmi * 64 + quad * 4;
  const int colb = n0 + wni * 64 + q15;
#pragma unroll
  for (int mq = 0; mq < 4; mq++)
#pragma unroll
    for (int nq = 0; nq < 4; nq++) {
      const f32x4 av = acc[mq][nq];
      const int row = rowb + mq * 16;
      const int col = colb + nq * 16;
      if (MODE == 4) {
        if (npart == 2) {          // k projection -> k_buf
          u16* Cout = (u16*)CoutV2;
          const int rk = row - NR;
          const int ck = col - 1280;
#pragma unroll
          for (int r = 0; r < 4; r++)
            Cout[(size_t)(rk + r) * HD + ck] = f2bf(av[r]);
        } else if (npart == 0) {   // q projection, row-major
          u16* Cout = (u16*)CoutV;
#pragma unroll
          for (int r = 0; r < 4; r++)
            Cout[(size_t)(row + r) * HD + col] = f2bf(av[r]);
        } else {                   // v projection, transposed store
          u16* Cout = (u16*)CoutV;
          const int vn = col - 640;
          const int bb = row >> 10;
          const int tl = row & 1023;
          u16x4 pk;
#pragma unroll
          for (int r = 0; r < 4; r++) pk[r] = f2bf(av[r]);
          *(u16x4*)&Cout[(size_t)(NR * HD) + ((size_t)(bb * HD + vn)) * TSEQ + tl] = pk;
        }
      } else {
        if (col < CC) {
          float* Cout = (float*)CoutV;
          const float bvv = bias[col];
#pragma unroll
          for (int r = 0; r < 4; r++)
            Cout[(size_t)(row + r) * CC + col] = av[r] + bvv;
        }
      }
    }
}

// ---------------- flash attention (r6 exact config: QBLK=128, 256 thr) -------
// q,k: [B,T,640] bf16 ; vt: [B,640,T] bf16 ; out attn: [16384][640] bf16 padded.
__global__ __launch_bounds__(256, 3) void attn_kernel(
    const u16* __restrict__ qb, const u16* __restrict__ kb,
    const u16* __restrict__ vt, u16* __restrict__ attn) {
  __shared__ u16 smem[11264 + 64 * 88 + 80 * 72];
  u16* Pt = smem;                       // per-wave [32 q][pitch 88]
  u16* Ks = smem + 11264;               // [64 s][88 pitch] (80 cols used)
  u16* Vs = smem + 11264 + 64 * 88;     // [80 d][72 pitch] (64 s cols used)

  const int tid  = threadIdx.x;
  const int lane = tid & 63;
  const int wave = tid >> 6;
  const int q15  = lane & 15;
  const int quad = lane >> 4;
  const int bid  = blockIdx.x;
  const int loc  = bid >> 3;
  const int pair = (bid & 7) * 16 + (loc >> 3);
  const int b  = pair >> 3;
  const int h  = pair & 7;
  const int t0 = (loc & 7) * 128;
  const int wq0 = wave * 32;
  const bool w3 = (tid < 128);          // waves 0,1 handle the 3rd chunk

  // staging geometry: K = 64 rows x 10 chunks; V = 80 rows x 8 chunks (640 each)
  int krow[3], kc[3], vrow[3], vc[3];
#pragma unroll
  for (int p = 0; p < 3; p++) {
    int qk = tid + 256 * p;
    krow[p] = qk / 10; kc[p] = (qk % 10) * 8;
    vrow[p] = qk >> 3; vc[p] = (qk & 7) * 8;
  }
  const u16* kbase = &kb[(size_t)(b * TSEQ) * HD + h * DP];
  const u16* vbase = &vt[(size_t)(b * HD + h * DP) * TSEQ];

  // Q fragments direct from global (B-operand of S^T); tail quads>=2 zeroed
  bf16x8 aq[2][2], aqt[2];
  {
    const u16x8 z = {0, 0, 0, 0, 0, 0, 0, 0};
#pragma unroll
    for (int n = 0; n < 2; n++) {
      const size_t qrow = (size_t)(b * TSEQ + t0 + wq0 + n * 16 + q15) * HD + h * DP;
#pragma unroll
      for (int kcx = 0; kcx < 2; kcx++)
        aq[n][kcx] = as_bf(*(const u16x8*)&qb[qrow + kcx * 32 + quad * 8]);
      u16x8 tload = z;
      if (quad < 2) tload = *(const u16x8*)&qb[qrow + 64 + quad * 8];
      aqt[n] = as_bf(tload);
    }
  }

  // zero pad cols 584..639 of this block's output rows
  if (tid < 128) {
    const u16x8 z = {0, 0, 0, 0, 0, 0, 0, 0};
    size_t base = (size_t)(b * TSEQ + t0 + tid) * KPW + CC;
#pragma unroll
    for (int c = 0; c < (KPW - CC) / 8; c++) *(u16x8*)&attn[base + c * 8] = z;
  }

  float lsum[2] = {0.f, 0.f};
  f32x4 oacc[2][5];
#pragma unroll
  for (int m = 0; m < 2; m++)
#pragma unroll
    for (int jd = 0; jd < 5; jd++) oacc[m][jd] = (f32x4){0.f, 0.f, 0.f, 0.f};

  u16* Ptw = &Pt[wave * 32 * PPITCH];

  u16x8 kreg[3], vreg[3];
#pragma unroll
  for (int p = 0; p < 2; p++) {
    kreg[p] = *(const u16x8*)&kbase[(size_t)krow[p] * HD + kc[p]];
    vreg[p] = *(const u16x8*)&vbase[(size_t)vrow[p] * TSEQ + vc[p]];
  }
  if (w3) {
    kreg[2] = *(const u16x8*)&kbase[(size_t)krow[2] * HD + kc[2]];
    vreg[2] = *(const u16x8*)&vbase[(size_t)vrow[2] * TSEQ + vc[2]];
  }

  for (int si = 0; si < 16; ++si) {
#pragma unroll
    for (int p = 0; p < 2; p++) {
      *(u16x8*)&Ks[krow[p] * 88 + kc[p]] = kreg[p];
      *(u16x8*)&Vs[vrow[p] * 72 + vc[p]] = vreg[p];
    }
    if (w3) {
      *(u16x8*)&Ks[krow[2] * 88 + kc[2]] = kreg[2];
      *(u16x8*)&Vs[vrow[2] * 72 + vc[2]] = vreg[2];
    }
    __syncthreads();

    if (si < 15) {
      const int s1 = (si + 1) * 64;
#pragma unroll
      for (int p = 0; p < 2; p++) {
        kreg[p] = *(const u16x8*)&kbase[(size_t)(s1 + krow[p]) * HD + kc[p]];
        vreg[p] = *(const u16x8*)&vbase[(size_t)vrow[p] * TSEQ + s1 + vc[p]];
      }
      if (w3) {
        kreg[2] = *(const u16x8*)&kbase[(size_t)(s1 + krow[2]) * HD + kc[2]];
        vreg[2] = *(const u16x8*)&vbase[(size_t)vrow[2] * TSEQ + s1 + vc[2]];
      }
    }

    // S^T = K Q^T : rows = s (4 tiles), cols = q (2 tiles)
    f32x4 st[4][2];
#pragma unroll
    for (int mt = 0; mt < 4; mt++)
#pragma unroll
      for (int n = 0; n < 2; n++) st[mt][n] = (f32x4){0.f, 0.f, 0.f, 0.f};
#pragma unroll
    for (int kcx = 0; kcx < 2; kcx++) {
      bf16x8 ak[4];
#pragma unroll
      for (int mt = 0; mt < 4; mt++)
        ak[mt] = as_bf(*(const u16x8*)&Ks[(mt * 16 + q15) * 88 + kcx * 32 + quad * 8]);
#pragma unroll
      for (int mt = 0; mt < 4; mt++)
#pragma unroll
        for (int n = 0; n < 2; n++)
          st[mt][n] = __builtin_amdgcn_mfma_f32_16x16x32_bf16(ak[mt], aq[n][kcx], st[mt][n], 0, 0, 0);
    }
    {  // tail: k 64..79 (quads >=2 zeroed on both operands)
      const u16x8 z = {0, 0, 0, 0, 0, 0, 0, 0};
#pragma unroll
      for (int mt = 0; mt < 4; mt++) {
        u16x8 tl = z;
        if (quad < 2) tl = *(const u16x8*)&Ks[(mt * 16 + q15) * 88 + 64 + quad * 8];
        bf16x8 akt = as_bf(tl);
#pragma unroll
        for (int n = 0; n < 2; n++)
          st[mt][n] = __builtin_amdgcn_mfma_f32_16x16x32_bf16(akt, aqt[n], st[mt][n], 0, 0, 0);
      }
    }

    // p = exp2(s*CEXP); per-lane partial row sums; vectorized Pt store (wave-private)
#pragma unroll
    for (int mt = 0; mt < 4; mt++)
#pragma unroll
      for (int n = 0; n < 2; n++) {
        f32x4 pv;
#pragma unroll
        for (int r = 0; r < 4; r++) pv[r] = __builtin_amdgcn_exp2f(st[mt][n][r] * CEXP);
        lsum[n] += (pv[0] + pv[1]) + (pv[2] + pv[3]);
        u16x4 pk;
#pragma unroll
        for (int r = 0; r < 4; r++) pk[r] = f2bf(pv[r]);
        *(u16x4*)&Ptw[(n * 16 + q15) * PPITCH + mt * 16 + quad * 4] = pk;
      }

    // O += P V  (A = P from Pt, b128 reads; B = V^T rows)
#pragma unroll
    for (int kcx = 0; kcx < 2; kcx++) {
      bf16x8 ap[2];
#pragma unroll
      for (int m = 0; m < 2; m++)
        ap[m] = as_bf(*(const u16x8*)&Ptw[(m * 16 + q15) * PPITCH + kcx * 32 + quad * 8]);
#pragma unroll
      for (int jd = 0; jd < 5; jd++) {
        bf16x8 bv = as_bf(*(const u16x8*)&Vs[(jd * 16 + q15) * 72 + kcx * 32 + quad * 8]);
#pragma unroll
        for (int m = 0; m < 2; m++)
          oacc[m][jd] = __builtin_amdgcn_mfma_f32_16x16x32_bf16(ap[m], bv, oacc[m][jd], 0, 0, 0);
      }
    }
    __syncthreads();
  }

  float lr[2];
#pragma unroll
  for (int n = 0; n < 2; n++) {
    float s = lsum[n];
    s += __shfl_xor(s, 16);
    s += __shfl_xor(s, 32);
    lr[n] = s;
  }

#pragma unroll
  for (int m = 0; m < 2; m++) {
#pragma unroll
    for (int r = 0; r < 4; r++) {
      const float inv = 1.f / __shfl(lr[m], quad * 4 + r);
      const int trow = t0 + wq0 + m * 16 + quad * 4 + r;
#pragma unroll
      for (int jd = 0; jd < 5; jd++) {
        const int d = jd * 16 + q15;
        if (d < DHD)
          attn[(size_t)(b * TSEQ + trow) * KPW + h * DHD + d] = f2bf(oacc[m][jd][r] * inv);
      }
    }
  }
}

// ---------------- launch ----------------

extern "C" void kernel_launch(void* const* d_in, const int* in_sizes, int n_in,
                              void* d_out, int out_size, void* d_ws, size_t ws_size,
                              hipStream_t stream) {
  const float* x   = (const float*)d_in[0];
  const float* mem = (const float*)d_in[1];
  const float* Wq  = (const float*)d_in[2];
  const float* Wk  = (const float*)d_in[3];
  const float* Wv  = (const float*)d_in[4];
  const float* Wp  = (const float*)d_in[5];
  const float* bp  = (const float*)d_in[6];
  float* out = (float*)d_out;

  char* ws = (char*)d_ws;
  const size_t SZ_XMB = (size_t)2 * NR * KPW * 2;  // 41,943,040
  const size_t SZ_WT  = (size_t)3 * HD * KPW * 2;  //  2,457,600 (q|v|k rows)
  const size_t SZ_WPT = (size_t)NP3 * KPW * 2;     //    983,040
  const size_t SZ_QB  = (size_t)NR * HD * 2;       // 20,971,520

  u16* xmb    = (u16*)(ws);            // [32768][640]; dead after projections
  u16* attn_o = (u16*)(ws);            // alias: [16384][640] padded
  u16* wt     = (u16*)(ws + SZ_XMB);
  u16* wp_t   = (u16*)(ws + SZ_XMB + SZ_WT);
  u16* q_buf  = (u16*)(ws + SZ_XMB + SZ_WT + SZ_WPT);       // q then vt contiguous
  u16* vt_buf = q_buf + (size_t)NR * HD;
  u16* k_buf  = (u16*)(ws + SZ_XMB + SZ_WT + SZ_WPT + 2 * SZ_QB);
  // total ws use: 41.9 + 2.5 + 1.0 + 62.9 MB ~= 108.3 MB

  (void)in_sizes; (void)n_in; (void)out_size; (void)ws_size;

  static bool s_attr = false;
  if (!s_attr) {
    (void)hipFuncSetAttribute((const void*)gemm8_kernel<4>,
                              hipFuncAttributeMaxDynamicSharedMemorySize, 65536);
    (void)hipFuncSetAttribute((const void*)gemm8_kernel<2>,
                              hipFuncAttributeMaxDynamicSharedMemorySize, 65536);
    s_attr = true;
  }

  // fused packs (2120 fat blocks)
  pack_all_kernel<<<PKA2 + PKB2 + PKC2, 256, 0, stream>>>(x, mem, Wq, Wk, Wv, Wp,
                                                          xmb, wt, wp_t);

  // all three projections in ONE launch; 1920 blocks, 2 blocks/CU
  gemm8_kernel<4><<<1920, 256, 65536, stream>>>(xmb, wt, q_buf, k_buf, nullptr);

  // attention (r6 config: 1024 blocks x 256 threads, 3 blocks/CU)
  attn_kernel<<<BB * HH * (TSEQ / 128), 256, 0, stream>>>(q_buf, k_buf, vt_buf, attn_o);

  // output projection + bias -> f32 out; 768 blocks, 2 blocks/CU
  gemm8_kernel<2><<<768, 256, 65536, stream>>>(attn_o, wp_t, out, nullptr, bp);
}